// Round 1
// baseline (4021.540 us; speedup 1.0000x reference)
//
#include <hip/hip_runtime.h>

// GCN, 4 layers, improved=True (self-loop weight 2.0), symmetric norm.
// N=50000 nodes, E=800000 edges, dims 16 -> 128 -> 128 -> 128 -> 16.
//
// Algebraic layout:
//   layer0: agg0 = A@x (16ch scatter), x1 = relu(agg0@w0 + b0)
//   layer1: h1 = x1@w1; agg1 = A@h1 + b1 (128ch scatter)
//   layer2: h2 = relu(agg1)@w2; agg2 = A@h2 + b2 (128ch scatter)
//   layer3: h3 = relu(agg2)@w3 (16ch); out = A@h3 + b3 (16ch scatter)
// Self-loop contribution (selfnorm[n]*h[n]) + bias initialize the agg
// buffer (no atomics); only edge messages use atomicAdd.

static constexpr int NN = 50000;
static constexpr int NE = 800000;

__global__ void init_deg_kernel(float* __restrict__ deg, int n) {
  int i = blockIdx.x * blockDim.x + threadIdx.x;
  if (i < n) deg[i] = 2.0f;  // self-loop weight (improved=True)
}

__global__ void accum_deg_kernel(const int* __restrict__ dst, const float* __restrict__ w,
                                 float* __restrict__ deg, int ne) {
  int i = blockIdx.x * blockDim.x + threadIdx.x;
  if (i < ne) atomicAdd(&deg[dst[i]], w[i]);
}

__global__ void finalize_dinv_kernel(float* __restrict__ deg_dinv,
                                     float* __restrict__ selfnorm, int n) {
  int i = blockIdx.x * blockDim.x + threadIdx.x;
  if (i < n) {
    float d = deg_dinv[i];
    float r = (d > 0.0f) ? rsqrtf(d) : 0.0f;
    deg_dinv[i] = r;                 // in-place deg -> dinv
    selfnorm[i] = 2.0f * r * r;      // norm of the self-loop edge
  }
}

__global__ void edge_norm_kernel(const int* __restrict__ src, const int* __restrict__ dst,
                                 const float* __restrict__ w, const float* __restrict__ dinv,
                                 float* __restrict__ norm, int ne) {
  int i = blockIdx.x * blockDim.x + threadIdx.x;
  if (i < ne) norm[i] = dinv[src[i]] * w[i] * dinv[dst[i]];
}

// agg[n][c] = selfnorm[n]*h[n][c] (+ bias[c])
template <int C, bool BIAS>
__global__ void agg_init_kernel(const float* __restrict__ h, const float* __restrict__ selfnorm,
                                const float* __restrict__ bias, float* __restrict__ agg, int n) {
  int i = blockIdx.x * blockDim.x + threadIdx.x;
  if (i >= n * C) return;
  int node = i / C;
  int c = i & (C - 1);
  float v = selfnorm[node] * h[i];
  if (BIAS) v += bias[c];
  agg[i] = v;
}

// agg[dst[e]][:] += norm[e] * h[src[e]][:], float4 per thread
template <int C>
__global__ void scatter_kernel(const float* __restrict__ h, const int* __restrict__ src,
                               const int* __restrict__ dst, const float* __restrict__ norm,
                               float* __restrict__ agg, int ne) {
  constexpr int GPE = C / 4;  // float4 groups per edge
  int idx = blockIdx.x * blockDim.x + threadIdx.x;
  int e = idx / GPE;
  if (e >= ne) return;
  int g = idx - e * GPE;
  float nm = norm[e];
  const float4 v = *(const float4*)(h + (size_t)src[e] * C + g * 4);
  float* ap = agg + (size_t)dst[e] * C + g * 4;
  atomicAdd(ap + 0, nm * v.x);
  atomicAdd(ap + 1, nm * v.y);
  atomicAdd(ap + 2, nm * v.z);
  atomicAdd(ap + 3, nm * v.w);
}

// out[r][c] = (bias) + sum_k act(in[r][k]) * w[k][c];  W staged in LDS.
template <int Cin, int Cout, bool RELU_IN, bool RELU_OUT, bool BIAS>
__global__ void gemm_kernel(const float* __restrict__ in, const float* __restrict__ w,
                            const float* __restrict__ bias, float* __restrict__ out, int n) {
  __shared__ float ws[Cin * Cout];
  for (int i = threadIdx.x; i < Cin * Cout; i += blockDim.x) ws[i] = w[i];
  __syncthreads();
  constexpr int RPB = 256 / Cout;  // rows per block
  int r = blockIdx.x * RPB + threadIdx.x / Cout;
  int c = threadIdx.x % Cout;
  if (r >= n) return;
  const float* xr = in + (size_t)r * Cin;
  float sum = BIAS ? bias[c] : 0.0f;
#pragma unroll
  for (int k = 0; k < Cin; ++k) {
    float v = xr[k];
    if (RELU_IN) v = fmaxf(v, 0.0f);
    sum = fmaf(v, ws[k * Cout + c], sum);
  }
  if (RELU_OUT) sum = fmaxf(sum, 0.0f);
  out[(size_t)r * Cout + c] = sum;
}

extern "C" void kernel_launch(void* const* d_in, const int* in_sizes, int n_in,
                              void* d_out, int out_size, void* d_ws, size_t ws_size,
                              hipStream_t stream) {
  const float* x  = (const float*)d_in[0];
  const int*   ei = (const int*)d_in[1];
  const float* ea = (const float*)d_in[2];
  const float* w0 = (const float*)d_in[3];
  const float* b0 = (const float*)d_in[4];
  const float* w1 = (const float*)d_in[5];
  const float* b1 = (const float*)d_in[6];
  const float* w2 = (const float*)d_in[7];
  const float* b2 = (const float*)d_in[8];
  const float* w3 = (const float*)d_in[9];
  const float* b3 = (const float*)d_in[10];
  float* out = (float*)d_out;

  const int* src = ei;        // edge_index[0]
  const int* dst = ei + NE;   // edge_index[1]

  float* wsf      = (float*)d_ws;
  float* dinv     = wsf;                       // [NN]  (deg, then dinv)
  float* selfnorm = wsf + NN;                  // [NN]
  float* norm     = wsf + 2 * NN;              // [NE]
  float* bufA     = norm + NE;                 // [NN*128]
  float* bufB     = bufA + (size_t)NN * 128;   // [NN*128]

  const int B = 256;
  auto blocks = [](long long t) { return (int)((t + 255) / 256); };

  // --- normalization precompute ---
  init_deg_kernel<<<blocks(NN), B, 0, stream>>>(dinv, NN);
  accum_deg_kernel<<<blocks(NE), B, 0, stream>>>(dst, ea, dinv, NE);
  finalize_dinv_kernel<<<blocks(NN), B, 0, stream>>>(dinv, selfnorm, NN);
  edge_norm_kernel<<<blocks(NE), B, 0, stream>>>(src, dst, ea, dinv, norm, NE);

  // --- layer 0: aggregate-first (16 ch), then GEMM+bias+relu ---
  agg_init_kernel<16, false><<<blocks((long long)NN * 16), B, 0, stream>>>(x, selfnorm, nullptr, bufA, NN);
  scatter_kernel<16><<<blocks((long long)NE * 4), B, 0, stream>>>(x, src, dst, norm, bufA, NE);
  gemm_kernel<16, 128, false, true, true><<<(NN + 1) / 2, B, 0, stream>>>(bufA, w0, b0, bufB, NN);

  // --- layer 1: GEMM, then aggregate (128 ch) ---
  gemm_kernel<128, 128, false, false, false><<<(NN + 1) / 2, B, 0, stream>>>(bufB, w1, nullptr, bufA, NN);
  agg_init_kernel<128, true><<<blocks((long long)NN * 128), B, 0, stream>>>(bufA, selfnorm, b1, bufB, NN);
  scatter_kernel<128><<<blocks((long long)NE * 32), B, 0, stream>>>(bufA, src, dst, norm, bufB, NE);

  // --- layer 2: relu on read, GEMM, aggregate (128 ch) ---
  gemm_kernel<128, 128, true, false, false><<<(NN + 1) / 2, B, 0, stream>>>(bufB, w2, nullptr, bufA, NN);
  agg_init_kernel<128, true><<<blocks((long long)NN * 128), B, 0, stream>>>(bufA, selfnorm, b2, bufB, NN);
  scatter_kernel<128><<<blocks((long long)NE * 32), B, 0, stream>>>(bufA, src, dst, norm, bufB, NE);

  // --- layer 3: relu on read, GEMM to 16 ch, aggregate into d_out ---
  gemm_kernel<128, 16, true, false, false><<<(NN + 15) / 16, B, 0, stream>>>(bufB, w3, nullptr, bufA, NN);
  agg_init_kernel<16, true><<<blocks((long long)NN * 16), B, 0, stream>>>(bufA, selfnorm, b3, out, NN);
  scatter_kernel<16><<<blocks((long long)NE * 4), B, 0, stream>>>(bufA, src, dst, norm, out, NE);
}

// Round 2
// 1423.113 us; speedup vs baseline: 2.8259x; 2.8259x over previous
//
#include <hip/hip_runtime.h>

// GCN, 4 layers, improved=True (self-loop weight 2.0), symmetric norm.
// N=50000 nodes, E=800000 edges, dims 16 -> 128 -> 128 -> 128 -> 16.
//
// Round 2: scatter+atomicAdd (1.6 GB atomic write traffic per 128-ch layer)
// replaced by device-built CSR + gather (25.6 MB sequential writes, 0 atomics).
//
//   CSR build: count in-degree -> 1-block scan -> fill packed (src,norm) int2.
//   layer0: agg0 = A@x (16ch gather), x1 = relu(agg0@w0 + b0)
//   layer1: h1 = x1@w1;        agg1 = A@h1 + b1 (128ch gather)
//   layer2: h2 = relu(agg1)@w2; agg2 = A@h2 + b2 (128ch gather)
//   layer3: h3 = relu(agg2)@w3; out  = A@h3 + b3 (16ch gather)

static constexpr int NN = 50000;
static constexpr int NE = 800000;

// deg = 2.0 (self-loop weight), cnt = 0
__global__ void init_kernel(float* __restrict__ deg, int* __restrict__ cnt, int n) {
  int i = blockIdx.x * blockDim.x + threadIdx.x;
  if (i < n) { deg[i] = 2.0f; cnt[i] = 0; }
}

// per-dst: in-degree count (for CSR) and weighted degree (for norm)
__global__ void count_kernel(const int* __restrict__ dst, const float* __restrict__ ea,
                             int* __restrict__ cnt, float* __restrict__ deg, int ne) {
  int i = blockIdx.x * blockDim.x + threadIdx.x;
  if (i < ne) {
    int d = dst[i];
    atomicAdd(&cnt[d], 1);
    atomicAdd(&deg[d], ea[i]);
  }
}

__global__ void finalize_dinv_kernel(float* __restrict__ deg_dinv,
                                     float* __restrict__ selfnorm, int n) {
  int i = blockIdx.x * blockDim.x + threadIdx.x;
  if (i < n) {
    float d = deg_dinv[i];
    float r = (d > 0.0f) ? rsqrtf(d) : 0.0f;
    deg_dinv[i] = r;             // in-place deg -> dinv
    selfnorm[i] = 2.0f * r * r;  // self-loop edge norm
  }
}

// exclusive prefix sum of cnt[0..n) -> rowptr[0..n] (in-place over cnt is OK:
// each thread reads its chunk into a register sum before any writes), and a
// second copy into fillpos. Single block of 1024.
__global__ void scan_kernel(int* __restrict__ cnt_rowptr, int* __restrict__ fillpos, int n) {
  __shared__ int lsum[1024];
  int t = threadIdx.x;
  const int chunk = (n + 1023) / 1024;
  int lo = t * chunk, hi = lo + chunk;
  if (hi > n) hi = n;
  int local[64];  // chunk = 49 for n = 50000
  int s = 0;
  for (int i = lo; i < hi; ++i) { local[i - lo] = cnt_rowptr[i]; s += local[i - lo]; }
  lsum[t] = s;
  __syncthreads();
  for (int off = 1; off < 1024; off <<= 1) {
    int v = (t >= off) ? lsum[t - off] : 0;
    __syncthreads();
    lsum[t] += v;
    __syncthreads();
  }
  int run = (t == 0) ? 0 : lsum[t - 1];
  for (int i = lo; i < hi; ++i) {
    cnt_rowptr[i] = run;
    fillpos[i] = run;
    run += local[i - lo];
  }
  if (t == 1023) cnt_rowptr[n] = lsum[1023];
}

// scatter each edge into its dst's CSR slot; store packed (src, norm)
__global__ void fill_kernel(const int* __restrict__ src, const int* __restrict__ dst,
                            const float* __restrict__ ea, const float* __restrict__ dinv,
                            int* __restrict__ fillpos, int2* __restrict__ csr, int ne) {
  int i = blockIdx.x * blockDim.x + threadIdx.x;
  if (i < ne) {
    int s = src[i], d = dst[i];
    int pos = atomicAdd(&fillpos[d], 1);
    int2 e;
    e.x = s;
    e.y = __float_as_int(dinv[s] * ea[i] * dinv[d]);
    csr[pos] = e;
  }
}

// agg[n][c] = bias[c] + selfnorm[n]*h[n][c] + sum_e norm[e]*h[src[e]][c]
template <int C, bool BIAS>
__global__ void gather_kernel(const float* __restrict__ h, const int* __restrict__ rowptr,
                              const int2* __restrict__ csr, const float* __restrict__ selfnorm,
                              const float* __restrict__ bias, float* __restrict__ agg, int n) {
  int node, c;
  if (C == 128) { node = blockIdx.x; c = threadIdx.x; }
  else { node = blockIdx.x * (256 / C) + threadIdx.x / C; c = threadIdx.x % C; }
  if (node >= n) return;
  float sum = selfnorm[node] * h[(size_t)node * C + c];
  if (BIAS) sum += bias[c];
  int e = rowptr[node], end = rowptr[node + 1];
  for (; e < end; ++e) {
    int2 ed = csr[e];
    sum = fmaf(__int_as_float(ed.y), h[(size_t)ed.x * C + c], sum);
  }
  agg[(size_t)node * C + c] = sum;
}

// out[r][c] = (bias) + sum_k act(in[r][k]) * w[k][c];  W staged in LDS.
template <int Cin, int Cout, bool RELU_IN, bool RELU_OUT, bool BIAS>
__global__ void gemm_kernel(const float* __restrict__ in, const float* __restrict__ w,
                            const float* __restrict__ bias, float* __restrict__ out, int n) {
  __shared__ float ws[Cin * Cout];
  for (int i = threadIdx.x; i < Cin * Cout; i += blockDim.x) ws[i] = w[i];
  __syncthreads();
  constexpr int RPB = 256 / Cout;  // rows per block
  int r = blockIdx.x * RPB + threadIdx.x / Cout;
  int c = threadIdx.x % Cout;
  if (r >= n) return;
  const float* xr = in + (size_t)r * Cin;
  float sum = BIAS ? bias[c] : 0.0f;
#pragma unroll
  for (int k = 0; k < Cin; ++k) {
    float v = xr[k];
    if (RELU_IN) v = fmaxf(v, 0.0f);
    sum = fmaf(v, ws[k * Cout + c], sum);
  }
  if (RELU_OUT) sum = fmaxf(sum, 0.0f);
  out[(size_t)r * Cout + c] = sum;
}

extern "C" void kernel_launch(void* const* d_in, const int* in_sizes, int n_in,
                              void* d_out, int out_size, void* d_ws, size_t ws_size,
                              hipStream_t stream) {
  const float* x  = (const float*)d_in[0];
  const int*   ei = (const int*)d_in[1];
  const float* ea = (const float*)d_in[2];
  const float* w0 = (const float*)d_in[3];
  const float* b0 = (const float*)d_in[4];
  const float* w1 = (const float*)d_in[5];
  const float* b1 = (const float*)d_in[6];
  const float* w2 = (const float*)d_in[7];
  const float* b2 = (const float*)d_in[8];
  const float* w3 = (const float*)d_in[9];
  const float* b3 = (const float*)d_in[10];
  float* out = (float*)d_out;

  const int* src = ei;       // edge_index[0]
  const int* dst = ei + NE;  // edge_index[1]

  // workspace layout (16-elem aligned regions)
  float* wsf      = (float*)d_ws;
  float* bufA     = wsf;                      // [NN*128]
  float* bufB     = bufA + (size_t)NN * 128;  // [NN*128]
  float* dinv     = bufB + (size_t)NN * 128;  // [NN]
  float* selfnorm = dinv + ((NN + 15) & ~15); // [NN]
  int*   rowptr   = (int*)(selfnorm + ((NN + 15) & ~15));  // [NN+1]
  int*   fillpos  = rowptr + ((NN + 1 + 15) & ~15);        // [NN]
  int2*  csr      = (int2*)(fillpos + ((NN + 15) & ~15));  // [NE]

  const int B = 256;
  auto blocks = [](long long t) { return (int)((t + 255) / 256); };

  // --- CSR + normalization build ---
  init_kernel<<<blocks(NN), B, 0, stream>>>(dinv, rowptr, NN);  // rowptr holds counts first
  count_kernel<<<blocks(NE), B, 0, stream>>>(dst, ea, rowptr, dinv, NE);
  finalize_dinv_kernel<<<blocks(NN), B, 0, stream>>>(dinv, selfnorm, NN);
  scan_kernel<<<1, 1024, 0, stream>>>(rowptr, fillpos, NN);
  fill_kernel<<<blocks(NE), B, 0, stream>>>(src, dst, ea, dinv, fillpos, csr, NE);

  // --- layer 0: aggregate-first (16 ch), then GEMM+bias+relu ---
  gather_kernel<16, false><<<(NN + 15) / 16, B, 0, stream>>>(x, rowptr, csr, selfnorm, nullptr, bufA, NN);
  gemm_kernel<16, 128, false, true, true><<<(NN + 1) / 2, B, 0, stream>>>(bufA, w0, b0, bufB, NN);

  // --- layer 1: GEMM, then aggregate (128 ch) ---
  gemm_kernel<128, 128, false, false, false><<<(NN + 1) / 2, B, 0, stream>>>(bufB, w1, nullptr, bufA, NN);
  gather_kernel<128, true><<<NN, 128, 0, stream>>>(bufA, rowptr, csr, selfnorm, b1, bufB, NN);

  // --- layer 2: relu on read, GEMM, aggregate (128 ch) ---
  gemm_kernel<128, 128, true, false, false><<<(NN + 1) / 2, B, 0, stream>>>(bufB, w2, nullptr, bufA, NN);
  gather_kernel<128, true><<<NN, 128, 0, stream>>>(bufA, rowptr, csr, selfnorm, b2, bufB, NN);

  // --- layer 3: relu on read, GEMM to 16 ch, aggregate into d_out ---
  gemm_kernel<128, 16, true, false, false><<<(NN + 15) / 16, B, 0, stream>>>(bufB, w3, nullptr, bufA, NN);
  gather_kernel<16, true><<<(NN + 15) / 16, B, 0, stream>>>(bufA, rowptr, csr, selfnorm, b3, out, NN);
}

// Round 3
// 570.073 us; speedup vs baseline: 7.0544x; 2.4964x over previous
//
#include <hip/hip_runtime.h>

// GCN, 4 layers, improved=True (self-loop weight 2.0), symmetric norm.
// N=50000 nodes, E=800000 edges, dims 16 -> 128 -> 128 -> 128 -> 16.
//
// R3: register-tiled fp32 GEMMs (4x8 acc/thread, input tile in padded LDS,
// W streamed from L1/L2) replacing the 1-output/thread latency-bound GEMM.
// CSR build + gather aggregation unchanged from R2.

static constexpr int NN = 50000;
static constexpr int NE = 800000;

// ---------------------------------------------------------------- CSR build

__global__ void init_kernel(float* __restrict__ deg, int* __restrict__ cnt, int n) {
  int i = blockIdx.x * blockDim.x + threadIdx.x;
  if (i < n) { deg[i] = 2.0f; cnt[i] = 0; }
}

__global__ void count_kernel(const int* __restrict__ dst, const float* __restrict__ ea,
                             int* __restrict__ cnt, float* __restrict__ deg, int ne) {
  int i = blockIdx.x * blockDim.x + threadIdx.x;
  if (i < ne) {
    int d = dst[i];
    atomicAdd(&cnt[d], 1);
    atomicAdd(&deg[d], ea[i]);
  }
}

__global__ void finalize_dinv_kernel(float* __restrict__ deg_dinv,
                                     float* __restrict__ selfnorm, int n) {
  int i = blockIdx.x * blockDim.x + threadIdx.x;
  if (i < n) {
    float d = deg_dinv[i];
    float r = (d > 0.0f) ? rsqrtf(d) : 0.0f;
    deg_dinv[i] = r;             // in-place deg -> dinv
    selfnorm[i] = 2.0f * r * r;  // self-loop edge norm
  }
}

// exclusive prefix sum of cnt[0..n) -> rowptr[0..n] (in-place safe: chunk is
// register-buffered before writes) + copy into fillpos. Single block of 1024.
__global__ void scan_kernel(int* __restrict__ cnt_rowptr, int* __restrict__ fillpos, int n) {
  __shared__ int lsum[1024];
  int t = threadIdx.x;
  const int chunk = (n + 1023) / 1024;
  int lo = t * chunk, hi = lo + chunk;
  if (hi > n) hi = n;
  int local[64];  // chunk = 49 for n = 50000
  int s = 0;
  for (int i = lo; i < hi; ++i) { local[i - lo] = cnt_rowptr[i]; s += local[i - lo]; }
  lsum[t] = s;
  __syncthreads();
  for (int off = 1; off < 1024; off <<= 1) {
    int v = (t >= off) ? lsum[t - off] : 0;
    __syncthreads();
    lsum[t] += v;
    __syncthreads();
  }
  int run = (t == 0) ? 0 : lsum[t - 1];
  for (int i = lo; i < hi; ++i) {
    cnt_rowptr[i] = run;
    fillpos[i] = run;
    run += local[i - lo];
  }
  if (t == 1023) cnt_rowptr[n] = lsum[1023];
}

__global__ void fill_kernel(const int* __restrict__ src, const int* __restrict__ dst,
                            const float* __restrict__ ea, const float* __restrict__ dinv,
                            int* __restrict__ fillpos, int2* __restrict__ csr, int ne) {
  int i = blockIdx.x * blockDim.x + threadIdx.x;
  if (i < ne) {
    int s = src[i], d = dst[i];
    int pos = atomicAdd(&fillpos[d], 1);
    int2 e;
    e.x = s;
    e.y = __float_as_int(dinv[s] * ea[i] * dinv[d]);
    csr[pos] = e;
  }
}

// ---------------------------------------------------------------- gather

// agg[n][c] = bias[c] + selfnorm[n]*h[n][c] + sum_e norm[e]*h[src[e]][c]
template <int C, bool BIAS>
__global__ void gather_kernel(const float* __restrict__ h, const int* __restrict__ rowptr,
                              const int2* __restrict__ csr, const float* __restrict__ selfnorm,
                              const float* __restrict__ bias, float* __restrict__ agg, int n) {
  int node, c;
  if (C == 128) { node = blockIdx.x; c = threadIdx.x; }
  else { node = blockIdx.x * (256 / C) + threadIdx.x / C; c = threadIdx.x % C; }
  if (node >= n) return;
  float sum = selfnorm[node] * h[(size_t)node * C + c];
  if (BIAS) sum += bias[c];
  int e = rowptr[node], end = rowptr[node + 1];
  for (; e < end; ++e) {
    int2 ed = csr[e];
    sum = fmaf(__int_as_float(ed.y), h[(size_t)ed.x * C + c], sum);
  }
  agg[(size_t)node * C + c] = sum;
}

// ---------------------------------------------------------------- GEMMs

// 128 -> 128: BM=64 rows/block, 256 thr = 16 rg x 16 cg, acc[4][8].
// Input tile in LDS [64][132] (pad -> conflict-free row reads), W from L1/L2.
template <bool RELU_IN>
__global__ void __launch_bounds__(256) gemm128x128_kernel(
    const float* __restrict__ in, const float* __restrict__ w, float* __restrict__ out, int n) {
  __shared__ float in_lds[64][132];
  const int row0 = blockIdx.x * 64;
  // stage input tile (relu applied here)
  for (int i = threadIdx.x; i < 64 * 32; i += 256) {
    int r = i >> 5, k4 = (i & 31) << 2;
    float4 v = make_float4(0.f, 0.f, 0.f, 0.f);
    if (row0 + r < n) v = *(const float4*)(in + (size_t)(row0 + r) * 128 + k4);
    if (RELU_IN) {
      v.x = fmaxf(v.x, 0.f); v.y = fmaxf(v.y, 0.f);
      v.z = fmaxf(v.z, 0.f); v.w = fmaxf(v.w, 0.f);
    }
    *(float4*)&in_lds[r][k4] = v;
  }
  __syncthreads();

  const int rg = threadIdx.x >> 4;         // 0..15 -> rows rg*4..rg*4+3
  const int c0 = (threadIdx.x & 15) << 3;  // 0..120
  float acc[4][8];
#pragma unroll
  for (int i = 0; i < 4; ++i)
#pragma unroll
    for (int j = 0; j < 8; ++j) acc[i][j] = 0.f;

#pragma unroll 4
  for (int k = 0; k < 128; ++k) {
    float a0 = in_lds[rg * 4 + 0][k];
    float a1 = in_lds[rg * 4 + 1][k];
    float a2 = in_lds[rg * 4 + 2][k];
    float a3 = in_lds[rg * 4 + 3][k];
    float4 bl = *(const float4*)(w + (size_t)k * 128 + c0);
    float4 bh = *(const float4*)(w + (size_t)k * 128 + c0 + 4);
    float b[8] = {bl.x, bl.y, bl.z, bl.w, bh.x, bh.y, bh.z, bh.w};
#pragma unroll
    for (int j = 0; j < 8; ++j) {
      acc[0][j] = fmaf(a0, b[j], acc[0][j]);
      acc[1][j] = fmaf(a1, b[j], acc[1][j]);
      acc[2][j] = fmaf(a2, b[j], acc[2][j]);
      acc[3][j] = fmaf(a3, b[j], acc[3][j]);
    }
  }
#pragma unroll
  for (int i = 0; i < 4; ++i) {
    int r = row0 + rg * 4 + i;
    if (r < n) {
      *(float4*)(out + (size_t)r * 128 + c0) = make_float4(acc[i][0], acc[i][1], acc[i][2], acc[i][3]);
      *(float4*)(out + (size_t)r * 128 + c0 + 4) = make_float4(acc[i][4], acc[i][5], acc[i][6], acc[i][7]);
    }
  }
}

// 16 -> 128 (layer 0): K=16 fully unrolled, W staged in LDS, +bias +relu out.
__global__ void __launch_bounds__(256) gemm16x128_kernel(
    const float* __restrict__ in, const float* __restrict__ w, const float* __restrict__ bias,
    float* __restrict__ out, int n) {
  __shared__ float in_lds[64][20];
  __shared__ float ws[16 * 128];
  __shared__ float bs[128];
  const int row0 = blockIdx.x * 64;
  for (int i = threadIdx.x; i < 16 * 32; i += 256)
    *(float4*)&ws[i * 4] = *(const float4*)(w + i * 4);
  if (threadIdx.x < 128) bs[threadIdx.x] = bias[threadIdx.x];
  for (int i = threadIdx.x; i < 64 * 4; i += 256) {
    int r = i >> 2, k4 = (i & 3) << 2;
    float4 v = make_float4(0.f, 0.f, 0.f, 0.f);
    if (row0 + r < n) v = *(const float4*)(in + (size_t)(row0 + r) * 16 + k4);
    *(float4*)&in_lds[r][k4] = v;
  }
  __syncthreads();

  const int rg = threadIdx.x >> 4;
  const int c0 = (threadIdx.x & 15) << 3;
  float acc[4][8];
#pragma unroll
  for (int i = 0; i < 4; ++i)
#pragma unroll
    for (int j = 0; j < 8; ++j) acc[i][j] = bs[c0 + j];

#pragma unroll
  for (int k = 0; k < 16; ++k) {
    float a0 = in_lds[rg * 4 + 0][k];
    float a1 = in_lds[rg * 4 + 1][k];
    float a2 = in_lds[rg * 4 + 2][k];
    float a3 = in_lds[rg * 4 + 3][k];
#pragma unroll
    for (int j = 0; j < 8; ++j) {
      float b = ws[k * 128 + c0 + j];
      acc[0][j] = fmaf(a0, b, acc[0][j]);
      acc[1][j] = fmaf(a1, b, acc[1][j]);
      acc[2][j] = fmaf(a2, b, acc[2][j]);
      acc[3][j] = fmaf(a3, b, acc[3][j]);
    }
  }
#pragma unroll
  for (int i = 0; i < 4; ++i) {
    int r = row0 + rg * 4 + i;
    if (r < n) {
#pragma unroll
      for (int j = 0; j < 8; ++j) acc[i][j] = fmaxf(acc[i][j], 0.f);
      *(float4*)(out + (size_t)r * 128 + c0) = make_float4(acc[i][0], acc[i][1], acc[i][2], acc[i][3]);
      *(float4*)(out + (size_t)r * 128 + c0 + 4) = make_float4(acc[i][4], acc[i][5], acc[i][6], acc[i][7]);
    }
  }
}

// 128 -> 16 (layer 3): relu on read, W (8 KB) in LDS, acc[4] per thread.
__global__ void __launch_bounds__(256) gemm128x16_kernel(
    const float* __restrict__ in, const float* __restrict__ w, float* __restrict__ out, int n) {
  __shared__ float in_lds[64][132];
  __shared__ float ws[128 * 16];
  const int row0 = blockIdx.x * 64;
  for (int i = threadIdx.x; i < 128 * 4; i += 256)
    *(float4*)&ws[i * 4] = *(const float4*)(w + i * 4);
  for (int i = threadIdx.x; i < 64 * 32; i += 256) {
    int r = i >> 5, k4 = (i & 31) << 2;
    float4 v = make_float4(0.f, 0.f, 0.f, 0.f);
    if (row0 + r < n) v = *(const float4*)(in + (size_t)(row0 + r) * 128 + k4);
    v.x = fmaxf(v.x, 0.f); v.y = fmaxf(v.y, 0.f);
    v.z = fmaxf(v.z, 0.f); v.w = fmaxf(v.w, 0.f);
    *(float4*)&in_lds[r][k4] = v;
  }
  __syncthreads();

  const int rg = threadIdx.x >> 4;        // 16 rowgroups x 4 rows
  const int c = threadIdx.x & 15;         // 16 cols
  float acc[4] = {0.f, 0.f, 0.f, 0.f};
#pragma unroll 4
  for (int k = 0; k < 128; ++k) {
    float b = ws[k * 16 + c];
    acc[0] = fmaf(in_lds[rg * 4 + 0][k], b, acc[0]);
    acc[1] = fmaf(in_lds[rg * 4 + 1][k], b, acc[1]);
    acc[2] = fmaf(in_lds[rg * 4 + 2][k], b, acc[2]);
    acc[3] = fmaf(in_lds[rg * 4 + 3][k], b, acc[3]);
  }
#pragma unroll
  for (int i = 0; i < 4; ++i) {
    int r = row0 + rg * 4 + i;
    if (r < n) out[(size_t)r * 16 + c] = acc[i];
  }
}

// ---------------------------------------------------------------- launch

extern "C" void kernel_launch(void* const* d_in, const int* in_sizes, int n_in,
                              void* d_out, int out_size, void* d_ws, size_t ws_size,
                              hipStream_t stream) {
  const float* x  = (const float*)d_in[0];
  const int*   ei = (const int*)d_in[1];
  const float* ea = (const float*)d_in[2];
  const float* w0 = (const float*)d_in[3];
  const float* b0 = (const float*)d_in[4];
  const float* w1 = (const float*)d_in[5];
  const float* b1 = (const float*)d_in[6];
  const float* w2 = (const float*)d_in[7];
  const float* b2 = (const float*)d_in[8];
  const float* w3 = (const float*)d_in[9];
  const float* b3 = (const float*)d_in[10];
  float* out = (float*)d_out;

  const int* src = ei;       // edge_index[0]
  const int* dst = ei + NE;  // edge_index[1]

  // workspace layout (16-elem aligned regions)
  float* wsf      = (float*)d_ws;
  float* bufA     = wsf;                      // [NN*128]
  float* bufB     = bufA + (size_t)NN * 128;  // [NN*128]
  float* dinv     = bufB + (size_t)NN * 128;  // [NN]
  float* selfnorm = dinv + ((NN + 15) & ~15); // [NN]
  int*   rowptr   = (int*)(selfnorm + ((NN + 15) & ~15));  // [NN+1]
  int*   fillpos  = rowptr + ((NN + 1 + 15) & ~15);        // [NN]
  int2*  csr      = (int2*)(fillpos + ((NN + 15) & ~15));  // [NE]

  const int B = 256;
  auto blocks = [](long long t) { return (int)((t + 255) / 256); };
  const int gemm_blocks = (NN + 63) / 64;  // 782

  // --- CSR + normalization build ---
  init_kernel<<<blocks(NN), B, 0, stream>>>(dinv, rowptr, NN);
  count_kernel<<<blocks(NE), B, 0, stream>>>(dst, ea, rowptr, dinv, NE);
  finalize_dinv_kernel<<<blocks(NN), B, 0, stream>>>(dinv, selfnorm, NN);
  scan_kernel<<<1, 1024, 0, stream>>>(rowptr, fillpos, NN);
  fill_kernel<<<blocks(NE), B, 0, stream>>>(src, dst, ea, dinv, fillpos, csr, NE);

  // --- layer 0: aggregate-first (16 ch), then GEMM+bias+relu ---
  gather_kernel<16, false><<<(NN + 15) / 16, B, 0, stream>>>(x, rowptr, csr, selfnorm, nullptr, bufA, NN);
  gemm16x128_kernel<<<gemm_blocks, B, 0, stream>>>(bufA, w0, b0, bufB, NN);

  // --- layer 1: GEMM, then aggregate (128 ch) ---
  gemm128x128_kernel<false><<<gemm_blocks, B, 0, stream>>>(bufB, w1, bufA, NN);
  gather_kernel<128, true><<<NN, 128, 0, stream>>>(bufA, rowptr, csr, selfnorm, b1, bufB, NN);

  // --- layer 2: relu on read, GEMM, aggregate (128 ch) ---
  gemm128x128_kernel<true><<<gemm_blocks, B, 0, stream>>>(bufB, w2, bufA, NN);
  gather_kernel<128, true><<<NN, 128, 0, stream>>>(bufA, rowptr, csr, selfnorm, b2, bufB, NN);

  // --- layer 3: relu on read, GEMM to 16 ch, aggregate into d_out ---
  gemm128x16_kernel<<<gemm_blocks, B, 0, stream>>>(bufB, w3, bufA, NN);
  gather_kernel<16, true><<<(NN + 15) / 16, B, 0, stream>>>(bufA, rowptr, csr, selfnorm, b3, out, NN);
}

// Round 4
// 468.050 us; speedup vs baseline: 8.5921x; 1.2180x over previous
//
#include <hip/hip_runtime.h>

// GCN, 4 layers, improved=True (self-loop weight 2.0), symmetric norm.
// N=50000 nodes, E=800000 edges, dims 16 -> 128 -> 128 -> 128 -> 16.
//
// R4: single-block scan (145 us, latency-bound on 1 CU) replaced by a
// 3-pass hierarchical scan (block-reduce -> scan block sums -> final).
// GEMMs (register-tiled) and CSR gather unchanged from R3.

static constexpr int NN = 50000;
static constexpr int NE = 800000;
static constexpr int SCAN_B = 256;                       // scan block size
static constexpr int SCAN_NB = (NN + SCAN_B - 1) / SCAN_B;  // 196

// ---------------------------------------------------------------- CSR build

__global__ void init_kernel(float* __restrict__ deg, int* __restrict__ cnt, int n) {
  int i = blockIdx.x * blockDim.x + threadIdx.x;
  if (i < n) { deg[i] = 2.0f; cnt[i] = 0; }
}

__global__ void count_kernel(const int* __restrict__ dst, const float* __restrict__ ea,
                             int* __restrict__ cnt, float* __restrict__ deg, int ne) {
  int i = blockIdx.x * blockDim.x + threadIdx.x;
  if (i < ne) {
    int d = dst[i];
    atomicAdd(&cnt[d], 1);
    atomicAdd(&deg[d], ea[i]);
  }
}

__global__ void finalize_dinv_kernel(float* __restrict__ deg_dinv,
                                     float* __restrict__ selfnorm, int n) {
  int i = blockIdx.x * blockDim.x + threadIdx.x;
  if (i < n) {
    float d = deg_dinv[i];
    float r = (d > 0.0f) ? rsqrtf(d) : 0.0f;
    deg_dinv[i] = r;             // in-place deg -> dinv
    selfnorm[i] = 2.0f * r * r;  // self-loop edge norm
  }
}

// pass 1: per-block sums of cnt
__global__ void block_reduce_kernel(const int* __restrict__ cnt, int* __restrict__ bsum, int n) {
  __shared__ int s[SCAN_B];
  int i = blockIdx.x * SCAN_B + threadIdx.x;
  s[threadIdx.x] = (i < n) ? cnt[i] : 0;
  __syncthreads();
  for (int off = SCAN_B / 2; off > 0; off >>= 1) {
    if (threadIdx.x < off) s[threadIdx.x] += s[threadIdx.x + off];
    __syncthreads();
  }
  if (threadIdx.x == 0) bsum[blockIdx.x] = s[0];
}

// pass 2: exclusive scan of bsum[nb] in one small block
__global__ void scan_bsums_kernel(int* __restrict__ bsum, int nb) {
  __shared__ int s[SCAN_B];
  int t = threadIdx.x;
  s[t] = (t < nb) ? bsum[t] : 0;
  __syncthreads();
  for (int off = 1; off < SCAN_B; off <<= 1) {
    int v = (t >= off) ? s[t - off] : 0;
    __syncthreads();
    s[t] += v;
    __syncthreads();
  }
  if (t < nb) bsum[t] = (t == 0) ? 0 : s[t - 1];  // exclusive
}

// pass 3: intra-block exclusive scan + block offset -> rowptr, fillpos.
// In-place over cnt (rowptr buffer) is safe: value is register-held, writes
// happen after all reads of this block's chunk, and blocks don't overlap.
__global__ void scan_final_kernel(int* __restrict__ cnt_rowptr, const int* __restrict__ bsum,
                                  int* __restrict__ fillpos, int n) {
  __shared__ int s[SCAN_B];
  int i = blockIdx.x * SCAN_B + threadIdx.x;
  int t = threadIdx.x;
  int v = (i < n) ? cnt_rowptr[i] : 0;
  s[t] = v;
  __syncthreads();
  for (int off = 1; off < SCAN_B; off <<= 1) {
    int u = (t >= off) ? s[t - off] : 0;
    __syncthreads();
    s[t] += u;
    __syncthreads();
  }
  int excl = bsum[blockIdx.x] + s[t] - v;  // exclusive prefix
  if (i < n) {
    cnt_rowptr[i] = excl;
    fillpos[i] = excl;
    if (i == n - 1) cnt_rowptr[n] = excl + v;  // total = NE
  }
}

__global__ void fill_kernel(const int* __restrict__ src, const int* __restrict__ dst,
                            const float* __restrict__ ea, const float* __restrict__ dinv,
                            int* __restrict__ fillpos, int2* __restrict__ csr, int ne) {
  int i = blockIdx.x * blockDim.x + threadIdx.x;
  if (i < ne) {
    int s = src[i], d = dst[i];
    int pos = atomicAdd(&fillpos[d], 1);
    int2 e;
    e.x = s;
    e.y = __float_as_int(dinv[s] * ea[i] * dinv[d]);
    csr[pos] = e;
  }
}

// ---------------------------------------------------------------- gather

// agg[n][c] = bias[c] + selfnorm[n]*h[n][c] + sum_e norm[e]*h[src[e]][c]
template <int C, bool BIAS>
__global__ void gather_kernel(const float* __restrict__ h, const int* __restrict__ rowptr,
                              const int2* __restrict__ csr, const float* __restrict__ selfnorm,
                              const float* __restrict__ bias, float* __restrict__ agg, int n) {
  int node, c;
  if (C == 128) { node = blockIdx.x; c = threadIdx.x; }
  else { node = blockIdx.x * (256 / C) + threadIdx.x / C; c = threadIdx.x % C; }
  if (node >= n) return;
  float sum = selfnorm[node] * h[(size_t)node * C + c];
  if (BIAS) sum += bias[c];
  int e = rowptr[node], end = rowptr[node + 1];
  for (; e < end; ++e) {
    int2 ed = csr[e];
    sum = fmaf(__int_as_float(ed.y), h[(size_t)ed.x * C + c], sum);
  }
  agg[(size_t)node * C + c] = sum;
}

// ---------------------------------------------------------------- GEMMs

// 128 -> 128: BM=64 rows/block, 256 thr = 16 rg x 16 cg, acc[4][8].
template <bool RELU_IN>
__global__ void __launch_bounds__(256) gemm128x128_kernel(
    const float* __restrict__ in, const float* __restrict__ w, float* __restrict__ out, int n) {
  __shared__ float in_lds[64][132];
  const int row0 = blockIdx.x * 64;
  for (int i = threadIdx.x; i < 64 * 32; i += 256) {
    int r = i >> 5, k4 = (i & 31) << 2;
    float4 v = make_float4(0.f, 0.f, 0.f, 0.f);
    if (row0 + r < n) v = *(const float4*)(in + (size_t)(row0 + r) * 128 + k4);
    if (RELU_IN) {
      v.x = fmaxf(v.x, 0.f); v.y = fmaxf(v.y, 0.f);
      v.z = fmaxf(v.z, 0.f); v.w = fmaxf(v.w, 0.f);
    }
    *(float4*)&in_lds[r][k4] = v;
  }
  __syncthreads();

  const int rg = threadIdx.x >> 4;
  const int c0 = (threadIdx.x & 15) << 3;
  float acc[4][8];
#pragma unroll
  for (int i = 0; i < 4; ++i)
#pragma unroll
    for (int j = 0; j < 8; ++j) acc[i][j] = 0.f;

#pragma unroll 4
  for (int k = 0; k < 128; ++k) {
    float a0 = in_lds[rg * 4 + 0][k];
    float a1 = in_lds[rg * 4 + 1][k];
    float a2 = in_lds[rg * 4 + 2][k];
    float a3 = in_lds[rg * 4 + 3][k];
    float4 bl = *(const float4*)(w + (size_t)k * 128 + c0);
    float4 bh = *(const float4*)(w + (size_t)k * 128 + c0 + 4);
    float b[8] = {bl.x, bl.y, bl.z, bl.w, bh.x, bh.y, bh.z, bh.w};
#pragma unroll
    for (int j = 0; j < 8; ++j) {
      acc[0][j] = fmaf(a0, b[j], acc[0][j]);
      acc[1][j] = fmaf(a1, b[j], acc[1][j]);
      acc[2][j] = fmaf(a2, b[j], acc[2][j]);
      acc[3][j] = fmaf(a3, b[j], acc[3][j]);
    }
  }
#pragma unroll
  for (int i = 0; i < 4; ++i) {
    int r = row0 + rg * 4 + i;
    if (r < n) {
      *(float4*)(out + (size_t)r * 128 + c0) = make_float4(acc[i][0], acc[i][1], acc[i][2], acc[i][3]);
      *(float4*)(out + (size_t)r * 128 + c0 + 4) = make_float4(acc[i][4], acc[i][5], acc[i][6], acc[i][7]);
    }
  }
}

// 16 -> 128 (layer 0): K=16 fully unrolled, W staged in LDS, +bias +relu out.
__global__ void __launch_bounds__(256) gemm16x128_kernel(
    const float* __restrict__ in, const float* __restrict__ w, const float* __restrict__ bias,
    float* __restrict__ out, int n) {
  __shared__ float in_lds[64][20];
  __shared__ float ws[16 * 128];
  __shared__ float bs[128];
  const int row0 = blockIdx.x * 64;
  for (int i = threadIdx.x; i < 16 * 32; i += 256)
    *(float4*)&ws[i * 4] = *(const float4*)(w + i * 4);
  if (threadIdx.x < 128) bs[threadIdx.x] = bias[threadIdx.x];
  for (int i = threadIdx.x; i < 64 * 4; i += 256) {
    int r = i >> 2, k4 = (i & 3) << 2;
    float4 v = make_float4(0.f, 0.f, 0.f, 0.f);
    if (row0 + r < n) v = *(const float4*)(in + (size_t)(row0 + r) * 16 + k4);
    *(float4*)&in_lds[r][k4] = v;
  }
  __syncthreads();

  const int rg = threadIdx.x >> 4;
  const int c0 = (threadIdx.x & 15) << 3;
  float acc[4][8];
#pragma unroll
  for (int i = 0; i < 4; ++i)
#pragma unroll
    for (int j = 0; j < 8; ++j) acc[i][j] = bs[c0 + j];

#pragma unroll
  for (int k = 0; k < 16; ++k) {
    float a0 = in_lds[rg * 4 + 0][k];
    float a1 = in_lds[rg * 4 + 1][k];
    float a2 = in_lds[rg * 4 + 2][k];
    float a3 = in_lds[rg * 4 + 3][k];
#pragma unroll
    for (int j = 0; j < 8; ++j) {
      float b = ws[k * 128 + c0 + j];
      acc[0][j] = fmaf(a0, b, acc[0][j]);
      acc[1][j] = fmaf(a1, b, acc[1][j]);
      acc[2][j] = fmaf(a2, b, acc[2][j]);
      acc[3][j] = fmaf(a3, b, acc[3][j]);
    }
  }
#pragma unroll
  for (int i = 0; i < 4; ++i) {
    int r = row0 + rg * 4 + i;
    if (r < n) {
#pragma unroll
      for (int j = 0; j < 8; ++j) acc[i][j] = fmaxf(acc[i][j], 0.f);
      *(float4*)(out + (size_t)r * 128 + c0) = make_float4(acc[i][0], acc[i][1], acc[i][2], acc[i][3]);
      *(float4*)(out + (size_t)r * 128 + c0 + 4) = make_float4(acc[i][4], acc[i][5], acc[i][6], acc[i][7]);
    }
  }
}

// 128 -> 16 (layer 3): relu on read, W (8 KB) in LDS, acc[4] per thread.
__global__ void __launch_bounds__(256) gemm128x16_kernel(
    const float* __restrict__ in, const float* __restrict__ w, float* __restrict__ out, int n) {
  __shared__ float in_lds[64][132];
  __shared__ float ws[128 * 16];
  const int row0 = blockIdx.x * 64;
  for (int i = threadIdx.x; i < 128 * 4; i += 256)
    *(float4*)&ws[i * 4] = *(const float4*)(w + i * 4);
  for (int i = threadIdx.x; i < 64 * 32; i += 256) {
    int r = i >> 5, k4 = (i & 31) << 2;
    float4 v = make_float4(0.f, 0.f, 0.f, 0.f);
    if (row0 + r < n) v = *(const float4*)(in + (size_t)(row0 + r) * 128 + k4);
    v.x = fmaxf(v.x, 0.f); v.y = fmaxf(v.y, 0.f);
    v.z = fmaxf(v.z, 0.f); v.w = fmaxf(v.w, 0.f);
    *(float4*)&in_lds[r][k4] = v;
  }
  __syncthreads();

  const int rg = threadIdx.x >> 4;
  const int c = threadIdx.x & 15;
  float acc[4] = {0.f, 0.f, 0.f, 0.f};
#pragma unroll 4
  for (int k = 0; k < 128; ++k) {
    float b = ws[k * 16 + c];
    acc[0] = fmaf(in_lds[rg * 4 + 0][k], b, acc[0]);
    acc[1] = fmaf(in_lds[rg * 4 + 1][k], b, acc[1]);
    acc[2] = fmaf(in_lds[rg * 4 + 2][k], b, acc[2]);
    acc[3] = fmaf(in_lds[rg * 4 + 3][k], b, acc[3]);
  }
#pragma unroll
  for (int i = 0; i < 4; ++i) {
    int r = row0 + rg * 4 + i;
    if (r < n) out[(size_t)r * 16 + c] = acc[i];
  }
}

// ---------------------------------------------------------------- launch

extern "C" void kernel_launch(void* const* d_in, const int* in_sizes, int n_in,
                              void* d_out, int out_size, void* d_ws, size_t ws_size,
                              hipStream_t stream) {
  const float* x  = (const float*)d_in[0];
  const int*   ei = (const int*)d_in[1];
  const float* ea = (const float*)d_in[2];
  const float* w0 = (const float*)d_in[3];
  const float* b0 = (const float*)d_in[4];
  const float* w1 = (const float*)d_in[5];
  const float* b1 = (const float*)d_in[6];
  const float* w2 = (const float*)d_in[7];
  const float* b2 = (const float*)d_in[8];
  const float* w3 = (const float*)d_in[9];
  const float* b3 = (const float*)d_in[10];
  float* out = (float*)d_out;

  const int* src = ei;       // edge_index[0]
  const int* dst = ei + NE;  // edge_index[1]

  // workspace layout (16-elem aligned regions)
  float* wsf      = (float*)d_ws;
  float* bufA     = wsf;                      // [NN*128]
  float* bufB     = bufA + (size_t)NN * 128;  // [NN*128]
  float* dinv     = bufB + (size_t)NN * 128;  // [NN]
  float* selfnorm = dinv + ((NN + 15) & ~15); // [NN]
  int*   rowptr   = (int*)(selfnorm + ((NN + 15) & ~15));  // [NN+1]
  int*   fillpos  = rowptr + ((NN + 1 + 15) & ~15);        // [NN]
  int*   bsum     = fillpos + ((NN + 15) & ~15);           // [SCAN_NB]
  int2*  csr      = (int2*)(bsum + ((SCAN_NB + 15) & ~15)); // [NE]

  const int B = 256;
  auto blocks = [](long long t) { return (int)((t + 255) / 256); };
  const int gemm_blocks = (NN + 63) / 64;  // 782

  // --- CSR + normalization build ---
  init_kernel<<<blocks(NN), B, 0, stream>>>(dinv, rowptr, NN);
  count_kernel<<<blocks(NE), B, 0, stream>>>(dst, ea, rowptr, dinv, NE);
  finalize_dinv_kernel<<<blocks(NN), B, 0, stream>>>(dinv, selfnorm, NN);
  block_reduce_kernel<<<SCAN_NB, SCAN_B, 0, stream>>>(rowptr, bsum, NN);
  scan_bsums_kernel<<<1, SCAN_B, 0, stream>>>(bsum, SCAN_NB);
  scan_final_kernel<<<SCAN_NB, SCAN_B, 0, stream>>>(rowptr, bsum, fillpos, NN);
  fill_kernel<<<blocks(NE), B, 0, stream>>>(src, dst, ea, dinv, fillpos, csr, NE);

  // --- layer 0: aggregate-first (16 ch), then GEMM+bias+relu ---
  gather_kernel<16, false><<<(NN + 15) / 16, B, 0, stream>>>(x, rowptr, csr, selfnorm, nullptr, bufA, NN);
  gemm16x128_kernel<<<gemm_blocks, B, 0, stream>>>(bufA, w0, b0, bufB, NN);

  // --- layer 1: GEMM, then aggregate (128 ch) ---
  gemm128x128_kernel<false><<<gemm_blocks, B, 0, stream>>>(bufB, w1, bufA, NN);
  gather_kernel<128, true><<<NN, 128, 0, stream>>>(bufA, rowptr, csr, selfnorm, b1, bufB, NN);

  // --- layer 2: relu on read, GEMM, aggregate (128 ch) ---
  gemm128x128_kernel<true><<<gemm_blocks, B, 0, stream>>>(bufB, w2, bufA, NN);
  gather_kernel<128, true><<<NN, 128, 0, stream>>>(bufA, rowptr, csr, selfnorm, b2, bufB, NN);

  // --- layer 3: relu on read, GEMM to 16 ch, aggregate into d_out ---
  gemm128x16_kernel<<<gemm_blocks, B, 0, stream>>>(bufB, w3, bufA, NN);
  gather_kernel<16, true><<<(NN + 15) / 16, B, 0, stream>>>(bufA, rowptr, csr, selfnorm, b3, out, NN);
}

// Round 5
// 378.350 us; speedup vs baseline: 10.6292x; 1.2371x over previous
//
#include <hip/hip_runtime.h>

// GCN, 4 layers, improved=True (self-loop weight 2.0), symmetric norm.
// N=50000 nodes, E=800000 edges, dims 16 -> 128 -> 128 -> 128 -> 16.
//
// R5: gather vectorized (float4/thread, 32 thr/node at C=128) + edge-loop
// unrolled x4 (4 outstanding row-reads) to break the memory-latency chain
// (R4 profile: gather<128> 90us, VALUBusy 6.7%, 31% HBM -> latency-bound).
// GEMMs, CSR build, hierarchical scan unchanged from R4.

static constexpr int NN = 50000;
static constexpr int NE = 800000;
static constexpr int SCAN_B = 256;
static constexpr int SCAN_NB = (NN + SCAN_B - 1) / SCAN_B;  // 196

// ---------------------------------------------------------------- CSR build

__global__ void init_kernel(float* __restrict__ deg, int* __restrict__ cnt, int n) {
  int i = blockIdx.x * blockDim.x + threadIdx.x;
  if (i < n) { deg[i] = 2.0f; cnt[i] = 0; }
}

__global__ void count_kernel(const int* __restrict__ dst, const float* __restrict__ ea,
                             int* __restrict__ cnt, float* __restrict__ deg, int ne) {
  int i = blockIdx.x * blockDim.x + threadIdx.x;
  if (i < ne) {
    int d = dst[i];
    atomicAdd(&cnt[d], 1);
    atomicAdd(&deg[d], ea[i]);
  }
}

__global__ void finalize_dinv_kernel(float* __restrict__ deg_dinv,
                                     float* __restrict__ selfnorm, int n) {
  int i = blockIdx.x * blockDim.x + threadIdx.x;
  if (i < n) {
    float d = deg_dinv[i];
    float r = (d > 0.0f) ? rsqrtf(d) : 0.0f;
    deg_dinv[i] = r;             // in-place deg -> dinv
    selfnorm[i] = 2.0f * r * r;  // self-loop edge norm
  }
}

__global__ void block_reduce_kernel(const int* __restrict__ cnt, int* __restrict__ bsum, int n) {
  __shared__ int s[SCAN_B];
  int i = blockIdx.x * SCAN_B + threadIdx.x;
  s[threadIdx.x] = (i < n) ? cnt[i] : 0;
  __syncthreads();
  for (int off = SCAN_B / 2; off > 0; off >>= 1) {
    if (threadIdx.x < off) s[threadIdx.x] += s[threadIdx.x + off];
    __syncthreads();
  }
  if (threadIdx.x == 0) bsum[blockIdx.x] = s[0];
}

__global__ void scan_bsums_kernel(int* __restrict__ bsum, int nb) {
  __shared__ int s[SCAN_B];
  int t = threadIdx.x;
  s[t] = (t < nb) ? bsum[t] : 0;
  __syncthreads();
  for (int off = 1; off < SCAN_B; off <<= 1) {
    int v = (t >= off) ? s[t - off] : 0;
    __syncthreads();
    s[t] += v;
    __syncthreads();
  }
  if (t < nb) bsum[t] = (t == 0) ? 0 : s[t - 1];  // exclusive
}

__global__ void scan_final_kernel(int* __restrict__ cnt_rowptr, const int* __restrict__ bsum,
                                  int* __restrict__ fillpos, int n) {
  __shared__ int s[SCAN_B];
  int i = blockIdx.x * SCAN_B + threadIdx.x;
  int t = threadIdx.x;
  int v = (i < n) ? cnt_rowptr[i] : 0;
  s[t] = v;
  __syncthreads();
  for (int off = 1; off < SCAN_B; off <<= 1) {
    int u = (t >= off) ? s[t - off] : 0;
    __syncthreads();
    s[t] += u;
    __syncthreads();
  }
  int excl = bsum[blockIdx.x] + s[t] - v;
  if (i < n) {
    cnt_rowptr[i] = excl;
    fillpos[i] = excl;
    if (i == n - 1) cnt_rowptr[n] = excl + v;  // total = NE
  }
}

__global__ void fill_kernel(const int* __restrict__ src, const int* __restrict__ dst,
                            const float* __restrict__ ea, const float* __restrict__ dinv,
                            int* __restrict__ fillpos, int2* __restrict__ csr, int ne) {
  int i = blockIdx.x * blockDim.x + threadIdx.x;
  if (i < ne) {
    int s = src[i], d = dst[i];
    int pos = atomicAdd(&fillpos[d], 1);
    int2 e;
    e.x = s;
    e.y = __float_as_int(dinv[s] * ea[i] * dinv[d]);
    csr[pos] = e;
  }
}

// ---------------------------------------------------------------- gather

// agg[n][c] = bias[c] + selfnorm[n]*h[n][c] + sum_e norm[e]*h[src[e]][c]
// float4 per thread; TPN = C/4 threads per node; edge loop unrolled x4.
template <int C, bool BIAS>
__global__ void __launch_bounds__(256) gather_kernel(
    const float* __restrict__ h, const int* __restrict__ rowptr,
    const int2* __restrict__ csr, const float* __restrict__ selfnorm,
    const float* __restrict__ bias, float* __restrict__ agg, int n) {
  constexpr int TPN = C / 4;    // threads per node (32 for C=128, 4 for C=16)
  constexpr int NPB = 256 / TPN;
  const int node = blockIdx.x * NPB + threadIdx.x / TPN;
  const int cg = threadIdx.x % TPN;  // float4 index within row
  if (node >= n) return;

  const float4* __restrict__ h4 = (const float4*)h;
  const float sn = selfnorm[node];
  float4 hv = h4[(size_t)node * TPN + cg];
  float4 acc;
  acc.x = sn * hv.x; acc.y = sn * hv.y; acc.z = sn * hv.z; acc.w = sn * hv.w;
  if (BIAS) {
    float4 bv = ((const float4*)bias)[cg];
    acc.x += bv.x; acc.y += bv.y; acc.z += bv.z; acc.w += bv.w;
  }

  int e = rowptr[node];
  const int end = rowptr[node + 1];
  for (; e + 4 <= end; e += 4) {
    int2 e0 = csr[e], e1 = csr[e + 1], e2 = csr[e + 2], e3 = csr[e + 3];
    float4 v0 = h4[(size_t)e0.x * TPN + cg];
    float4 v1 = h4[(size_t)e1.x * TPN + cg];
    float4 v2 = h4[(size_t)e2.x * TPN + cg];
    float4 v3 = h4[(size_t)e3.x * TPN + cg];
    float n0 = __int_as_float(e0.y), n1 = __int_as_float(e1.y);
    float n2 = __int_as_float(e2.y), n3 = __int_as_float(e3.y);
    acc.x = fmaf(n0, v0.x, acc.x); acc.y = fmaf(n0, v0.y, acc.y);
    acc.z = fmaf(n0, v0.z, acc.z); acc.w = fmaf(n0, v0.w, acc.w);
    acc.x = fmaf(n1, v1.x, acc.x); acc.y = fmaf(n1, v1.y, acc.y);
    acc.z = fmaf(n1, v1.z, acc.z); acc.w = fmaf(n1, v1.w, acc.w);
    acc.x = fmaf(n2, v2.x, acc.x); acc.y = fmaf(n2, v2.y, acc.y);
    acc.z = fmaf(n2, v2.z, acc.z); acc.w = fmaf(n2, v2.w, acc.w);
    acc.x = fmaf(n3, v3.x, acc.x); acc.y = fmaf(n3, v3.y, acc.y);
    acc.z = fmaf(n3, v3.z, acc.z); acc.w = fmaf(n3, v3.w, acc.w);
  }
  for (; e < end; ++e) {
    int2 ed = csr[e];
    float4 v = h4[(size_t)ed.x * TPN + cg];
    float nm = __int_as_float(ed.y);
    acc.x = fmaf(nm, v.x, acc.x); acc.y = fmaf(nm, v.y, acc.y);
    acc.z = fmaf(nm, v.z, acc.z); acc.w = fmaf(nm, v.w, acc.w);
  }
  ((float4*)agg)[(size_t)node * TPN + cg] = acc;
}

// ---------------------------------------------------------------- GEMMs

// 128 -> 128: BM=64 rows/block, 256 thr = 16 rg x 16 cg, acc[4][8].
template <bool RELU_IN>
__global__ void __launch_bounds__(256) gemm128x128_kernel(
    const float* __restrict__ in, const float* __restrict__ w, float* __restrict__ out, int n) {
  __shared__ float in_lds[64][132];
  const int row0 = blockIdx.x * 64;
  for (int i = threadIdx.x; i < 64 * 32; i += 256) {
    int r = i >> 5, k4 = (i & 31) << 2;
    float4 v = make_float4(0.f, 0.f, 0.f, 0.f);
    if (row0 + r < n) v = *(const float4*)(in + (size_t)(row0 + r) * 128 + k4);
    if (RELU_IN) {
      v.x = fmaxf(v.x, 0.f); v.y = fmaxf(v.y, 0.f);
      v.z = fmaxf(v.z, 0.f); v.w = fmaxf(v.w, 0.f);
    }
    *(float4*)&in_lds[r][k4] = v;
  }
  __syncthreads();

  const int rg = threadIdx.x >> 4;
  const int c0 = (threadIdx.x & 15) << 3;
  float acc[4][8];
#pragma unroll
  for (int i = 0; i < 4; ++i)
#pragma unroll
    for (int j = 0; j < 8; ++j) acc[i][j] = 0.f;

#pragma unroll 4
  for (int k = 0; k < 128; ++k) {
    float a0 = in_lds[rg * 4 + 0][k];
    float a1 = in_lds[rg * 4 + 1][k];
    float a2 = in_lds[rg * 4 + 2][k];
    float a3 = in_lds[rg * 4 + 3][k];
    float4 bl = *(const float4*)(w + (size_t)k * 128 + c0);
    float4 bh = *(const float4*)(w + (size_t)k * 128 + c0 + 4);
    float b[8] = {bl.x, bl.y, bl.z, bl.w, bh.x, bh.y, bh.z, bh.w};
#pragma unroll
    for (int j = 0; j < 8; ++j) {
      acc[0][j] = fmaf(a0, b[j], acc[0][j]);
      acc[1][j] = fmaf(a1, b[j], acc[1][j]);
      acc[2][j] = fmaf(a2, b[j], acc[2][j]);
      acc[3][j] = fmaf(a3, b[j], acc[3][j]);
    }
  }
#pragma unroll
  for (int i = 0; i < 4; ++i) {
    int r = row0 + rg * 4 + i;
    if (r < n) {
      *(float4*)(out + (size_t)r * 128 + c0) = make_float4(acc[i][0], acc[i][1], acc[i][2], acc[i][3]);
      *(float4*)(out + (size_t)r * 128 + c0 + 4) = make_float4(acc[i][4], acc[i][5], acc[i][6], acc[i][7]);
    }
  }
}

// 16 -> 128 (layer 0): K=16 fully unrolled, W staged in LDS, +bias +relu out.
__global__ void __launch_bounds__(256) gemm16x128_kernel(
    const float* __restrict__ in, const float* __restrict__ w, const float* __restrict__ bias,
    float* __restrict__ out, int n) {
  __shared__ float in_lds[64][20];
  __shared__ float ws[16 * 128];
  __shared__ float bs[128];
  const int row0 = blockIdx.x * 64;
  for (int i = threadIdx.x; i < 16 * 32; i += 256)
    *(float4*)&ws[i * 4] = *(const float4*)(w + i * 4);
  if (threadIdx.x < 128) bs[threadIdx.x] = bias[threadIdx.x];
  for (int i = threadIdx.x; i < 64 * 4; i += 256) {
    int r = i >> 2, k4 = (i & 3) << 2;
    float4 v = make_float4(0.f, 0.f, 0.f, 0.f);
    if (row0 + r < n) v = *(const float4*)(in + (size_t)(row0 + r) * 16 + k4);
    *(float4*)&in_lds[r][k4] = v;
  }
  __syncthreads();

  const int rg = threadIdx.x >> 4;
  const int c0 = (threadIdx.x & 15) << 3;
  float acc[4][8];
#pragma unroll
  for (int i = 0; i < 4; ++i)
#pragma unroll
    for (int j = 0; j < 8; ++j) acc[i][j] = bs[c0 + j];

#pragma unroll
  for (int k = 0; k < 16; ++k) {
    float a0 = in_lds[rg * 4 + 0][k];
    float a1 = in_lds[rg * 4 + 1][k];
    float a2 = in_lds[rg * 4 + 2][k];
    float a3 = in_lds[rg * 4 + 3][k];
#pragma unroll
    for (int j = 0; j < 8; ++j) {
      float b = ws[k * 128 + c0 + j];
      acc[0][j] = fmaf(a0, b, acc[0][j]);
      acc[1][j] = fmaf(a1, b, acc[1][j]);
      acc[2][j] = fmaf(a2, b, acc[2][j]);
      acc[3][j] = fmaf(a3, b, acc[3][j]);
    }
  }
#pragma unroll
  for (int i = 0; i < 4; ++i) {
    int r = row0 + rg * 4 + i;
    if (r < n) {
#pragma unroll
      for (int j = 0; j < 8; ++j) acc[i][j] = fmaxf(acc[i][j], 0.f);
      *(float4*)(out + (size_t)r * 128 + c0) = make_float4(acc[i][0], acc[i][1], acc[i][2], acc[i][3]);
      *(float4*)(out + (size_t)r * 128 + c0 + 4) = make_float4(acc[i][4], acc[i][5], acc[i][6], acc[i][7]);
    }
  }
}

// 128 -> 16 (layer 3): relu on read, W (8 KB) in LDS, acc[4] per thread.
__global__ void __launch_bounds__(256) gemm128x16_kernel(
    const float* __restrict__ in, const float* __restrict__ w, float* __restrict__ out, int n) {
  __shared__ float in_lds[64][132];
  __shared__ float ws[128 * 16];
  const int row0 = blockIdx.x * 64;
  for (int i = threadIdx.x; i < 128 * 4; i += 256)
    *(float4*)&ws[i * 4] = *(const float4*)(w + i * 4);
  for (int i = threadIdx.x; i < 64 * 32; i += 256) {
    int r = i >> 5, k4 = (i & 31) << 2;
    float4 v = make_float4(0.f, 0.f, 0.f, 0.f);
    if (row0 + r < n) v = *(const float4*)(in + (size_t)(row0 + r) * 128 + k4);
    v.x = fmaxf(v.x, 0.f); v.y = fmaxf(v.y, 0.f);
    v.z = fmaxf(v.z, 0.f); v.w = fmaxf(v.w, 0.f);
    *(float4*)&in_lds[r][k4] = v;
  }
  __syncthreads();

  const int rg = threadIdx.x >> 4;
  const int c = threadIdx.x & 15;
  float acc[4] = {0.f, 0.f, 0.f, 0.f};
#pragma unroll 4
  for (int k = 0; k < 128; ++k) {
    float b = ws[k * 16 + c];
    acc[0] = fmaf(in_lds[rg * 4 + 0][k], b, acc[0]);
    acc[1] = fmaf(in_lds[rg * 4 + 1][k], b, acc[1]);
    acc[2] = fmaf(in_lds[rg * 4 + 2][k], b, acc[2]);
    acc[3] = fmaf(in_lds[rg * 4 + 3][k], b, acc[3]);
  }
#pragma unroll
  for (int i = 0; i < 4; ++i) {
    int r = row0 + rg * 4 + i;
    if (r < n) out[(size_t)r * 16 + c] = acc[i];
  }
}

// ---------------------------------------------------------------- launch

extern "C" void kernel_launch(void* const* d_in, const int* in_sizes, int n_in,
                              void* d_out, int out_size, void* d_ws, size_t ws_size,
                              hipStream_t stream) {
  const float* x  = (const float*)d_in[0];
  const int*   ei = (const int*)d_in[1];
  const float* ea = (const float*)d_in[2];
  const float* w0 = (const float*)d_in[3];
  const float* b0 = (const float*)d_in[4];
  const float* w1 = (const float*)d_in[5];
  const float* b1 = (const float*)d_in[6];
  const float* w2 = (const float*)d_in[7];
  const float* b2 = (const float*)d_in[8];
  const float* w3 = (const float*)d_in[9];
  const float* b3 = (const float*)d_in[10];
  float* out = (float*)d_out;

  const int* src = ei;       // edge_index[0]
  const int* dst = ei + NE;  // edge_index[1]

  // workspace layout (16-elem aligned regions)
  float* wsf      = (float*)d_ws;
  float* bufA     = wsf;                      // [NN*128]
  float* bufB     = bufA + (size_t)NN * 128;  // [NN*128]
  float* dinv     = bufB + (size_t)NN * 128;  // [NN]
  float* selfnorm = dinv + ((NN + 15) & ~15); // [NN]
  int*   rowptr   = (int*)(selfnorm + ((NN + 15) & ~15));  // [NN+1]
  int*   fillpos  = rowptr + ((NN + 1 + 15) & ~15);        // [NN]
  int*   bsum     = fillpos + ((NN + 15) & ~15);           // [SCAN_NB]
  int2*  csr      = (int2*)(bsum + ((SCAN_NB + 15) & ~15)); // [NE]

  const int B = 256;
  auto blocks = [](long long t) { return (int)((t + 255) / 256); };
  const int gemm_blocks = (NN + 63) / 64;  // 782

  // --- CSR + normalization build ---
  init_kernel<<<blocks(NN), B, 0, stream>>>(dinv, rowptr, NN);
  count_kernel<<<blocks(NE), B, 0, stream>>>(dst, ea, rowptr, dinv, NE);
  finalize_dinv_kernel<<<blocks(NN), B, 0, stream>>>(dinv, selfnorm, NN);
  block_reduce_kernel<<<SCAN_NB, SCAN_B, 0, stream>>>(rowptr, bsum, NN);
  scan_bsums_kernel<<<1, SCAN_B, 0, stream>>>(bsum, SCAN_NB);
  scan_final_kernel<<<SCAN_NB, SCAN_B, 0, stream>>>(rowptr, bsum, fillpos, NN);
  fill_kernel<<<blocks(NE), B, 0, stream>>>(src, dst, ea, dinv, fillpos, csr, NE);

  // --- layer 0: aggregate-first (16 ch), then GEMM+bias+relu ---
  gather_kernel<16, false><<<(NN + 63) / 64, B, 0, stream>>>(x, rowptr, csr, selfnorm, nullptr, bufA, NN);
  gemm16x128_kernel<<<gemm_blocks, B, 0, stream>>>(bufA, w0, b0, bufB, NN);

  // --- layer 1: GEMM, then aggregate (128 ch) ---
  gemm128x128_kernel<false><<<gemm_blocks, B, 0, stream>>>(bufB, w1, bufA, NN);
  gather_kernel<128, true><<<(NN + 7) / 8, B, 0, stream>>>(bufA, rowptr, csr, selfnorm, b1, bufB, NN);

  // --- layer 2: relu on read, GEMM, aggregate (128 ch) ---
  gemm128x128_kernel<true><<<gemm_blocks, B, 0, stream>>>(bufB, w2, bufA, NN);
  gather_kernel<128, true><<<(NN + 7) / 8, B, 0, stream>>>(bufA, rowptr, csr, selfnorm, b2, bufB, NN);

  // --- layer 3: relu on read, GEMM to 16 ch, aggregate into d_out ---
  gemm128x16_kernel<<<gemm_blocks, B, 0, stream>>>(bufB, w3, bufA, NN);
  gather_kernel<16, true><<<(NN + 63) / 64, B, 0, stream>>>(bufA, rowptr, csr, selfnorm, b3, out, NN);
}

// Round 6
// 356.638 us; speedup vs baseline: 11.2762x; 1.0609x over previous
//
#include <hip/hip_runtime.h>

// GCN, 4 layers, improved=True (self-loop weight 2.0), symmetric norm.
// N=50000 nodes, E=800000 edges, dims 16 -> 128 -> 128 -> 128 -> 16.
//
// R6: normalization refactor. agg[n] = dinv[n]*(sum_e w_e*g[src]) + 2*dinv[n]*g[n] + b
// with g = dinv (.) h (row-scale folded into producer-GEMM epilogue).
//  - count_kernel: int atomic only (800k fabric RMWs instead of 1.6M)
//  - fill_kernel: stores (src, raw ea); no dinv gathers
//  - deg computed AFTER CSR build by sequential per-row sum (no atomics)
//  - gather: 8-deep edge unroll for more memory-level parallelism

static constexpr int NN = 50000;
static constexpr int NE = 800000;
static constexpr int SCAN_B = 256;
static constexpr int SCAN_NB = (NN + SCAN_B - 1) / SCAN_B;  // 196

// ---------------------------------------------------------------- CSR build

__global__ void init_kernel(int* __restrict__ cnt, int n) {
  int i = blockIdx.x * blockDim.x + threadIdx.x;
  if (i < n) cnt[i] = 0;
}

__global__ void count_kernel(const int* __restrict__ dst, int* __restrict__ cnt, int ne) {
  int i = blockIdx.x * blockDim.x + threadIdx.x;
  if (i < ne) atomicAdd(&cnt[dst[i]], 1);
}

__global__ void block_reduce_kernel(const int* __restrict__ cnt, int* __restrict__ bsum, int n) {
  __shared__ int s[SCAN_B];
  int i = blockIdx.x * SCAN_B + threadIdx.x;
  s[threadIdx.x] = (i < n) ? cnt[i] : 0;
  __syncthreads();
  for (int off = SCAN_B / 2; off > 0; off >>= 1) {
    if (threadIdx.x < off) s[threadIdx.x] += s[threadIdx.x + off];
    __syncthreads();
  }
  if (threadIdx.x == 0) bsum[blockIdx.x] = s[0];
}

__global__ void scan_bsums_kernel(int* __restrict__ bsum, int nb) {
  __shared__ int s[SCAN_B];
  int t = threadIdx.x;
  s[t] = (t < nb) ? bsum[t] : 0;
  __syncthreads();
  for (int off = 1; off < SCAN_B; off <<= 1) {
    int v = (t >= off) ? s[t - off] : 0;
    __syncthreads();
    s[t] += v;
    __syncthreads();
  }
  if (t < nb) bsum[t] = (t == 0) ? 0 : s[t - 1];  // exclusive
}

__global__ void scan_final_kernel(int* __restrict__ cnt_rowptr, const int* __restrict__ bsum,
                                  int* __restrict__ fillpos, int n) {
  __shared__ int s[SCAN_B];
  int i = blockIdx.x * SCAN_B + threadIdx.x;
  int t = threadIdx.x;
  int v = (i < n) ? cnt_rowptr[i] : 0;
  s[t] = v;
  __syncthreads();
  for (int off = 1; off < SCAN_B; off <<= 1) {
    int u = (t >= off) ? s[t - off] : 0;
    __syncthreads();
    s[t] += u;
    __syncthreads();
  }
  int excl = bsum[blockIdx.x] + s[t] - v;
  if (i < n) {
    cnt_rowptr[i] = excl;
    fillpos[i] = excl;
    if (i == n - 1) cnt_rowptr[n] = excl + v;  // total = NE
  }
}

__global__ void fill_kernel(const int* __restrict__ src, const int* __restrict__ dst,
                            const float* __restrict__ ea,
                            int* __restrict__ fillpos, int2* __restrict__ csr, int ne) {
  int i = blockIdx.x * blockDim.x + threadIdx.x;
  if (i < ne) {
    int pos = atomicAdd(&fillpos[dst[i]], 1);
    csr[pos] = make_int2(src[i], __float_as_int(ea[i]));
  }
}

// deg[n] = 2 (self-loop) + sum of raw edge weights over the CSR row; dinv = rsqrt.
__global__ void row_deg_kernel(const int* __restrict__ rowptr, const int2* __restrict__ csr,
                               float* __restrict__ dinv, int n) {
  int i = blockIdx.x * blockDim.x + threadIdx.x;
  if (i >= n) return;
  int e = rowptr[i], end = rowptr[i + 1];
  float d = 2.0f;
  for (; e < end; ++e) d += __int_as_float(csr[e].y);
  dinv[i] = rsqrtf(d);  // d >= 2 always (ea >= 0)
}

// xs[n][c] = dinv[n] * x[n][c]  (C=16, one float4 per thread)
__global__ void xscale_kernel(const float* __restrict__ x, const float* __restrict__ dinv,
                              float* __restrict__ xs, int n) {
  int i = blockIdx.x * blockDim.x + threadIdx.x;  // float4 index
  if (i >= n * 4) return;
  float dn = dinv[i >> 2];
  float4 v = ((const float4*)x)[i];
  v.x *= dn; v.y *= dn; v.z *= dn; v.w *= dn;
  ((float4*)xs)[i] = v;
}

// ---------------------------------------------------------------- gather

// agg[n][c] = dinv[n]*( sum_e w_e*g[src][c] + 2*g[n][c] ) + bias[c]
// g is the dinv-prescaled feature buffer. float4/thread, 8-deep edge unroll.
template <int C, bool BIAS>
__global__ void __launch_bounds__(256) gather_kernel(
    const float* __restrict__ g, const int* __restrict__ rowptr,
    const int2* __restrict__ csr, const float* __restrict__ dinv,
    const float* __restrict__ bias, float* __restrict__ agg, int n) {
  constexpr int TPN = C / 4;    // threads per node (32 for C=128, 4 for C=16)
  constexpr int NPB = 256 / TPN;
  const int node = blockIdx.x * NPB + threadIdx.x / TPN;
  const int cg = threadIdx.x % TPN;
  if (node >= n) return;

  const float4* __restrict__ g4 = (const float4*)g;
  float4 gs = g4[(size_t)node * TPN + cg];
  float4 acc = make_float4(2.f * gs.x, 2.f * gs.y, 2.f * gs.z, 2.f * gs.w);

  int e = rowptr[node];
  const int end = rowptr[node + 1];
  for (; e + 8 <= end; e += 8) {
    int2 ed[8];
#pragma unroll
    for (int j = 0; j < 8; ++j) ed[j] = csr[e + j];
    float4 v[8];
#pragma unroll
    for (int j = 0; j < 8; ++j) v[j] = g4[(size_t)ed[j].x * TPN + cg];
#pragma unroll
    for (int j = 0; j < 8; ++j) {
      float w = __int_as_float(ed[j].y);
      acc.x = fmaf(w, v[j].x, acc.x); acc.y = fmaf(w, v[j].y, acc.y);
      acc.z = fmaf(w, v[j].z, acc.z); acc.w = fmaf(w, v[j].w, acc.w);
    }
  }
  for (; e + 4 <= end; e += 4) {
    int2 e0 = csr[e], e1 = csr[e + 1], e2 = csr[e + 2], e3 = csr[e + 3];
    float4 v0 = g4[(size_t)e0.x * TPN + cg];
    float4 v1 = g4[(size_t)e1.x * TPN + cg];
    float4 v2 = g4[(size_t)e2.x * TPN + cg];
    float4 v3 = g4[(size_t)e3.x * TPN + cg];
    float n0 = __int_as_float(e0.y), n1 = __int_as_float(e1.y);
    float n2 = __int_as_float(e2.y), n3 = __int_as_float(e3.y);
    acc.x = fmaf(n0, v0.x, acc.x); acc.y = fmaf(n0, v0.y, acc.y);
    acc.z = fmaf(n0, v0.z, acc.z); acc.w = fmaf(n0, v0.w, acc.w);
    acc.x = fmaf(n1, v1.x, acc.x); acc.y = fmaf(n1, v1.y, acc.y);
    acc.z = fmaf(n1, v1.z, acc.z); acc.w = fmaf(n1, v1.w, acc.w);
    acc.x = fmaf(n2, v2.x, acc.x); acc.y = fmaf(n2, v2.y, acc.y);
    acc.z = fmaf(n2, v2.z, acc.z); acc.w = fmaf(n2, v2.w, acc.w);
    acc.x = fmaf(n3, v3.x, acc.x); acc.y = fmaf(n3, v3.y, acc.y);
    acc.z = fmaf(n3, v3.z, acc.z); acc.w = fmaf(n3, v3.w, acc.w);
  }
  for (; e < end; ++e) {
    int2 ed = csr[e];
    float4 v = g4[(size_t)ed.x * TPN + cg];
    float w = __int_as_float(ed.y);
    acc.x = fmaf(w, v.x, acc.x); acc.y = fmaf(w, v.y, acc.y);
    acc.z = fmaf(w, v.z, acc.z); acc.w = fmaf(w, v.w, acc.w);
  }

  const float dn = dinv[node];
  float4 res = make_float4(dn * acc.x, dn * acc.y, dn * acc.z, dn * acc.w);
  if (BIAS) {
    float4 bv = ((const float4*)bias)[cg];
    res.x += bv.x; res.y += bv.y; res.z += bv.z; res.w += bv.w;
  }
  ((float4*)agg)[(size_t)node * TPN + cg] = res;
}

// ---------------------------------------------------------------- GEMMs

// 128 -> 128: BM=64, 256 thr = 16 rg x 16 cg, acc[4][8]; epilogue row-scale by dinv.
template <bool RELU_IN>
__global__ void __launch_bounds__(256) gemm128x128_kernel(
    const float* __restrict__ in, const float* __restrict__ w, const float* __restrict__ dinv,
    float* __restrict__ out, int n) {
  __shared__ float in_lds[64][132];
  const int row0 = blockIdx.x * 64;
  for (int i = threadIdx.x; i < 64 * 32; i += 256) {
    int r = i >> 5, k4 = (i & 31) << 2;
    float4 v = make_float4(0.f, 0.f, 0.f, 0.f);
    if (row0 + r < n) v = *(const float4*)(in + (size_t)(row0 + r) * 128 + k4);
    if (RELU_IN) {
      v.x = fmaxf(v.x, 0.f); v.y = fmaxf(v.y, 0.f);
      v.z = fmaxf(v.z, 0.f); v.w = fmaxf(v.w, 0.f);
    }
    *(float4*)&in_lds[r][k4] = v;
  }
  __syncthreads();

  const int rg = threadIdx.x >> 4;
  const int c0 = (threadIdx.x & 15) << 3;
  float acc[4][8];
#pragma unroll
  for (int i = 0; i < 4; ++i)
#pragma unroll
    for (int j = 0; j < 8; ++j) acc[i][j] = 0.f;

#pragma unroll 4
  for (int k = 0; k < 128; ++k) {
    float a0 = in_lds[rg * 4 + 0][k];
    float a1 = in_lds[rg * 4 + 1][k];
    float a2 = in_lds[rg * 4 + 2][k];
    float a3 = in_lds[rg * 4 + 3][k];
    float4 bl = *(const float4*)(w + (size_t)k * 128 + c0);
    float4 bh = *(const float4*)(w + (size_t)k * 128 + c0 + 4);
    float b[8] = {bl.x, bl.y, bl.z, bl.w, bh.x, bh.y, bh.z, bh.w};
#pragma unroll
    for (int j = 0; j < 8; ++j) {
      acc[0][j] = fmaf(a0, b[j], acc[0][j]);
      acc[1][j] = fmaf(a1, b[j], acc[1][j]);
      acc[2][j] = fmaf(a2, b[j], acc[2][j]);
      acc[3][j] = fmaf(a3, b[j], acc[3][j]);
    }
  }
#pragma unroll
  for (int i = 0; i < 4; ++i) {
    int r = row0 + rg * 4 + i;
    if (r < n) {
      float dn = dinv[r];
      *(float4*)(out + (size_t)r * 128 + c0) =
          make_float4(dn * acc[i][0], dn * acc[i][1], dn * acc[i][2], dn * acc[i][3]);
      *(float4*)(out + (size_t)r * 128 + c0 + 4) =
          make_float4(dn * acc[i][4], dn * acc[i][5], dn * acc[i][6], dn * acc[i][7]);
    }
  }
}

// 16 -> 128 (layer 0): K=16 fully unrolled, W in LDS, +bias +relu out (NO dinv scale:
// output x1 feeds the next GEMM, not a gather).
__global__ void __launch_bounds__(256) gemm16x128_kernel(
    const float* __restrict__ in, const float* __restrict__ w, const float* __restrict__ bias,
    float* __restrict__ out, int n) {
  __shared__ float in_lds[64][20];
  __shared__ float ws[16 * 128];
  __shared__ float bs[128];
  const int row0 = blockIdx.x * 64;
  for (int i = threadIdx.x; i < 16 * 32; i += 256)
    *(float4*)&ws[i * 4] = *(const float4*)(w + i * 4);
  if (threadIdx.x < 128) bs[threadIdx.x] = bias[threadIdx.x];
  for (int i = threadIdx.x; i < 64 * 4; i += 256) {
    int r = i >> 2, k4 = (i & 3) << 2;
    float4 v = make_float4(0.f, 0.f, 0.f, 0.f);
    if (row0 + r < n) v = *(const float4*)(in + (size_t)(row0 + r) * 16 + k4);
    *(float4*)&in_lds[r][k4] = v;
  }
  __syncthreads();

  const int rg = threadIdx.x >> 4;
  const int c0 = (threadIdx.x & 15) << 3;
  float acc[4][8];
#pragma unroll
  for (int i = 0; i < 4; ++i)
#pragma unroll
    for (int j = 0; j < 8; ++j) acc[i][j] = bs[c0 + j];

#pragma unroll
  for (int k = 0; k < 16; ++k) {
    float a0 = in_lds[rg * 4 + 0][k];
    float a1 = in_lds[rg * 4 + 1][k];
    float a2 = in_lds[rg * 4 + 2][k];
    float a3 = in_lds[rg * 4 + 3][k];
#pragma unroll
    for (int j = 0; j < 8; ++j) {
      float b = ws[k * 128 + c0 + j];
      acc[0][j] = fmaf(a0, b, acc[0][j]);
      acc[1][j] = fmaf(a1, b, acc[1][j]);
      acc[2][j] = fmaf(a2, b, acc[2][j]);
      acc[3][j] = fmaf(a3, b, acc[3][j]);
    }
  }
#pragma unroll
  for (int i = 0; i < 4; ++i) {
    int r = row0 + rg * 4 + i;
    if (r < n) {
#pragma unroll
      for (int j = 0; j < 8; ++j) acc[i][j] = fmaxf(acc[i][j], 0.f);
      *(float4*)(out + (size_t)r * 128 + c0) = make_float4(acc[i][0], acc[i][1], acc[i][2], acc[i][3]);
      *(float4*)(out + (size_t)r * 128 + c0 + 4) = make_float4(acc[i][4], acc[i][5], acc[i][6], acc[i][7]);
    }
  }
}

// 128 -> 16 (layer 3): relu on read, W in LDS, acc[4]/thread; epilogue dinv scale.
__global__ void __launch_bounds__(256) gemm128x16_kernel(
    const float* __restrict__ in, const float* __restrict__ w, const float* __restrict__ dinv,
    float* __restrict__ out, int n) {
  __shared__ float in_lds[64][132];
  __shared__ float ws[128 * 16];
  const int row0 = blockIdx.x * 64;
  for (int i = threadIdx.x; i < 128 * 4; i += 256)
    *(float4*)&ws[i * 4] = *(const float4*)(w + i * 4);
  for (int i = threadIdx.x; i < 64 * 32; i += 256) {
    int r = i >> 5, k4 = (i & 31) << 2;
    float4 v = make_float4(0.f, 0.f, 0.f, 0.f);
    if (row0 + r < n) v = *(const float4*)(in + (size_t)(row0 + r) * 128 + k4);
    v.x = fmaxf(v.x, 0.f); v.y = fmaxf(v.y, 0.f);
    v.z = fmaxf(v.z, 0.f); v.w = fmaxf(v.w, 0.f);
    *(float4*)&in_lds[r][k4] = v;
  }
  __syncthreads();

  const int rg = threadIdx.x >> 4;
  const int c = threadIdx.x & 15;
  float acc[4] = {0.f, 0.f, 0.f, 0.f};
#pragma unroll 4
  for (int k = 0; k < 128; ++k) {
    float b = ws[k * 16 + c];
    acc[0] = fmaf(in_lds[rg * 4 + 0][k], b, acc[0]);
    acc[1] = fmaf(in_lds[rg * 4 + 1][k], b, acc[1]);
    acc[2] = fmaf(in_lds[rg * 4 + 2][k], b, acc[2]);
    acc[3] = fmaf(in_lds[rg * 4 + 3][k], b, acc[3]);
  }
#pragma unroll
  for (int i = 0; i < 4; ++i) {
    int r = row0 + rg * 4 + i;
    if (r < n) out[(size_t)r * 16 + c] = dinv[r] * acc[i];
  }
}

// ---------------------------------------------------------------- launch

extern "C" void kernel_launch(void* const* d_in, const int* in_sizes, int n_in,
                              void* d_out, int out_size, void* d_ws, size_t ws_size,
                              hipStream_t stream) {
  const float* x  = (const float*)d_in[0];
  const int*   ei = (const int*)d_in[1];
  const float* ea = (const float*)d_in[2];
  const float* w0 = (const float*)d_in[3];
  const float* b0 = (const float*)d_in[4];
  const float* w1 = (const float*)d_in[5];
  const float* b1 = (const float*)d_in[6];
  const float* w2 = (const float*)d_in[7];
  const float* b2 = (const float*)d_in[8];
  const float* w3 = (const float*)d_in[9];
  const float* b3 = (const float*)d_in[10];
  float* out = (float*)d_out;

  const int* src = ei;       // edge_index[0]
  const int* dst = ei + NE;  // edge_index[1]

  // workspace layout (16-elem aligned regions)
  float* wsf      = (float*)d_ws;
  float* bufA     = wsf;                      // [NN*128]
  float* bufB     = bufA + (size_t)NN * 128;  // [NN*128]  (also hosts xs = dinv.x, 16ch)
  float* dinv     = bufB + (size_t)NN * 128;  // [NN]
  int*   rowptr   = (int*)(dinv + ((NN + 15) & ~15));      // [NN+1]
  int*   fillpos  = rowptr + ((NN + 1 + 15) & ~15);        // [NN]
  int*   bsum     = fillpos + ((NN + 15) & ~15);           // [SCAN_NB]
  int2*  csr      = (int2*)(bsum + ((SCAN_NB + 15) & ~15)); // [NE]

  const int B = 256;
  auto blocks = [](long long t) { return (int)((t + 255) / 256); };
  const int gemm_blocks = (NN + 63) / 64;  // 782

  // --- CSR build + normalization (no dinv dependency until row_deg) ---
  init_kernel<<<blocks(NN), B, 0, stream>>>(rowptr, NN);  // rowptr holds counts first
  count_kernel<<<blocks(NE), B, 0, stream>>>(dst, rowptr, NE);
  block_reduce_kernel<<<SCAN_NB, SCAN_B, 0, stream>>>(rowptr, bsum, NN);
  scan_bsums_kernel<<<1, SCAN_B, 0, stream>>>(bsum, SCAN_NB);
  scan_final_kernel<<<SCAN_NB, SCAN_B, 0, stream>>>(rowptr, bsum, fillpos, NN);
  fill_kernel<<<blocks(NE), B, 0, stream>>>(src, dst, ea, fillpos, csr, NE);
  row_deg_kernel<<<blocks(NN), B, 0, stream>>>(rowptr, csr, dinv, NN);

  // --- layer 0: xs = dinv.x (in bufB), gather (16 ch) -> bufA, GEMM+bias+relu -> bufB ---
  xscale_kernel<<<blocks((long long)NN * 4), B, 0, stream>>>(x, dinv, bufB, NN);
  gather_kernel<16, false><<<(NN + 63) / 64, B, 0, stream>>>(bufB, rowptr, csr, dinv, nullptr, bufA, NN);
  gemm16x128_kernel<<<gemm_blocks, B, 0, stream>>>(bufA, w0, b0, bufB, NN);

  // --- layer 1: GEMM (scale out) -> g1 in bufA, gather -> agg1 in bufB ---
  gemm128x128_kernel<false><<<gemm_blocks, B, 0, stream>>>(bufB, w1, dinv, bufA, NN);
  gather_kernel<128, true><<<(NN + 7) / 8, B, 0, stream>>>(bufA, rowptr, csr, dinv, b1, bufB, NN);

  // --- layer 2: relu on read, GEMM (scale out) -> g2, gather -> agg2 ---
  gemm128x128_kernel<true><<<gemm_blocks, B, 0, stream>>>(bufB, w2, dinv, bufA, NN);
  gather_kernel<128, true><<<(NN + 7) / 8, B, 0, stream>>>(bufA, rowptr, csr, dinv, b2, bufB, NN);

  // --- layer 3: relu on read, GEMM to 16 (scale out) -> g3, gather -> out ---
  gemm128x16_kernel<<<gemm_blocks, B, 0, stream>>>(bufB, w3, dinv, bufA, NN);
  gather_kernel<16, true><<<(NN + 63) / 64, B, 0, stream>>>(bufA, rowptr, csr, dinv, b3, out, NN);
}

// Round 7
// 324.846 us; speedup vs baseline: 12.3798x; 1.0979x over previous
//
#include <hip/hip_runtime.h>

// GCN, 4 layers, improved=True (self-loop weight 2.0), symmetric norm.
// N=50000 nodes, E=800000 edges, dims 16 -> 128 -> 128 -> 128 -> 16.
//
// R7: (a) capacity-padded CSR (CAP=64 slots/node) removes the count pass
// (800k atomics) and the 3-kernel scan entirely -- one fill pass claims
// slots directly; cnt[] doubles as row length. Guarded by ws_size with
// fallback to the R6 compact-CSR path. (b) gather<128> restructured to
// 16 threads/node (2 x float4 per thread) halving duplicated csr loads
// and doubling bytes-in-flight per thread.

static constexpr int NN = 50000;
static constexpr int NE = 800000;
static constexpr int CAP = 64;  // max degree capacity (Poisson(16), 12 sigma)
static constexpr int SCAN_B = 256;
static constexpr int SCAN_NB = (NN + SCAN_B - 1) / SCAN_B;  // 196

// ---------------------------------------------------------------- common

__global__ void init_kernel(int* __restrict__ cnt, int n) {
  int i = blockIdx.x * blockDim.x + threadIdx.x;
  if (i < n) cnt[i] = 0;
}

// xs[n][c] = dinv[n] * x[n][c]  (C=16, one float4 per thread)
__global__ void xscale_kernel(const float* __restrict__ x, const float* __restrict__ dinv,
                              float* __restrict__ xs, int n) {
  int i = blockIdx.x * blockDim.x + threadIdx.x;  // float4 index
  if (i >= n * 4) return;
  float dn = dinv[i >> 2];
  float4 v = ((const float4*)x)[i];
  v.x *= dn; v.y *= dn; v.z *= dn; v.w *= dn;
  ((float4*)xs)[i] = v;
}

// ---------------------------------------------------------------- padded-CSR path

__global__ void fill_pad_kernel(const int* __restrict__ src, const int* __restrict__ dst,
                                const float* __restrict__ ea,
                                int* __restrict__ cnt, int2* __restrict__ csr, int ne) {
  int i = blockIdx.x * blockDim.x + threadIdx.x;
  if (i < ne) {
    int d = dst[i];
    int slot = atomicAdd(&cnt[d], 1);
    csr[(size_t)d * CAP + slot] = make_int2(src[i], __float_as_int(ea[i]));
  }
}

__global__ void row_deg_pad_kernel(const int* __restrict__ cnt, const int2* __restrict__ csr,
                                   float* __restrict__ dinv, int n) {
  int i = blockIdx.x * blockDim.x + threadIdx.x;
  if (i >= n) return;
  const int2* row = csr + (size_t)i * CAP;
  int c = cnt[i];
  float d = 2.0f;
  for (int e = 0; e < c; ++e) d += __int_as_float(row[e].y);
  dinv[i] = rsqrtf(d);  // d >= 2 always (ea >= 0)
}

// agg[n][c] = dinv[n]*( sum_e w_e*g[src][c] + 2*g[n][c] ) + bias[c]
// TPN=16 for C=128 (2 float4/thread), TPN=4 for C=16 (1 float4/thread).
template <int C, bool BIAS>
__global__ void __launch_bounds__(256) gather_pad_kernel(
    const float* __restrict__ g, const int* __restrict__ cnt,
    const int2* __restrict__ csr, const float* __restrict__ dinv,
    const float* __restrict__ bias, float* __restrict__ agg, int n) {
  constexpr int TPN = (C == 128) ? 16 : 4;
  constexpr int VEC = C / (4 * TPN);     // float4s per thread (2 or 1)
  constexpr int NPB = 256 / TPN;
  constexpr int RS = C / 4;              // row stride in float4
  const int node = blockIdx.x * NPB + threadIdx.x / TPN;
  const int cg = threadIdx.x % TPN;
  if (node >= n) return;

  const float4* __restrict__ g4 = (const float4*)g;
  float4 acc[VEC];
#pragma unroll
  for (int u = 0; u < VEC; ++u) {
    float4 t = g4[(size_t)node * RS + cg * VEC + u];
    acc[u] = make_float4(2.f * t.x, 2.f * t.y, 2.f * t.z, 2.f * t.w);
  }

  const int2* __restrict__ row = csr + (size_t)node * CAP;
  const int cn = cnt[node];
  int e = 0;
  for (; e + 4 <= cn; e += 4) {
    int2 ed[4];
#pragma unroll
    for (int j = 0; j < 4; ++j) ed[j] = row[e + j];
    float4 v[4][VEC];
#pragma unroll
    for (int j = 0; j < 4; ++j)
#pragma unroll
      for (int u = 0; u < VEC; ++u) v[j][u] = g4[(size_t)ed[j].x * RS + cg * VEC + u];
#pragma unroll
    for (int j = 0; j < 4; ++j) {
      float w = __int_as_float(ed[j].y);
#pragma unroll
      for (int u = 0; u < VEC; ++u) {
        acc[u].x = fmaf(w, v[j][u].x, acc[u].x);
        acc[u].y = fmaf(w, v[j][u].y, acc[u].y);
        acc[u].z = fmaf(w, v[j][u].z, acc[u].z);
        acc[u].w = fmaf(w, v[j][u].w, acc[u].w);
      }
    }
  }
  for (; e < cn; ++e) {
    int2 ed = row[e];
    float w = __int_as_float(ed.y);
#pragma unroll
    for (int u = 0; u < VEC; ++u) {
      float4 v = g4[(size_t)ed.x * RS + cg * VEC + u];
      acc[u].x = fmaf(w, v.x, acc[u].x);
      acc[u].y = fmaf(w, v.y, acc[u].y);
      acc[u].z = fmaf(w, v.z, acc[u].z);
      acc[u].w = fmaf(w, v.w, acc[u].w);
    }
  }

  const float dn = dinv[node];
#pragma unroll
  for (int u = 0; u < VEC; ++u) {
    float4 res = make_float4(dn * acc[u].x, dn * acc[u].y, dn * acc[u].z, dn * acc[u].w);
    if (BIAS) {
      float4 bv = ((const float4*)bias)[cg * VEC + u];
      res.x += bv.x; res.y += bv.y; res.z += bv.z; res.w += bv.w;
    }
    ((float4*)agg)[(size_t)node * RS + cg * VEC + u] = res;
  }
}

// ---------------------------------------------------------------- compact-CSR fallback (R6)

__global__ void count_kernel(const int* __restrict__ dst, int* __restrict__ cnt, int ne) {
  int i = blockIdx.x * blockDim.x + threadIdx.x;
  if (i < ne) atomicAdd(&cnt[dst[i]], 1);
}

__global__ void block_reduce_kernel(const int* __restrict__ cnt, int* __restrict__ bsum, int n) {
  __shared__ int s[SCAN_B];
  int i = blockIdx.x * SCAN_B + threadIdx.x;
  s[threadIdx.x] = (i < n) ? cnt[i] : 0;
  __syncthreads();
  for (int off = SCAN_B / 2; off > 0; off >>= 1) {
    if (threadIdx.x < off) s[threadIdx.x] += s[threadIdx.x + off];
    __syncthreads();
  }
  if (threadIdx.x == 0) bsum[blockIdx.x] = s[0];
}

__global__ void scan_bsums_kernel(int* __restrict__ bsum, int nb) {
  __shared__ int s[SCAN_B];
  int t = threadIdx.x;
  s[t] = (t < nb) ? bsum[t] : 0;
  __syncthreads();
  for (int off = 1; off < SCAN_B; off <<= 1) {
    int v = (t >= off) ? s[t - off] : 0;
    __syncthreads();
    s[t] += v;
    __syncthreads();
  }
  if (t < nb) bsum[t] = (t == 0) ? 0 : s[t - 1];  // exclusive
}

__global__ void scan_final_kernel(int* __restrict__ cnt_rowptr, const int* __restrict__ bsum,
                                  int* __restrict__ fillpos, int n) {
  __shared__ int s[SCAN_B];
  int i = blockIdx.x * SCAN_B + threadIdx.x;
  int t = threadIdx.x;
  int v = (i < n) ? cnt_rowptr[i] : 0;
  s[t] = v;
  __syncthreads();
  for (int off = 1; off < SCAN_B; off <<= 1) {
    int u = (t >= off) ? s[t - off] : 0;
    __syncthreads();
    s[t] += u;
    __syncthreads();
  }
  int excl = bsum[blockIdx.x] + s[t] - v;
  if (i < n) {
    cnt_rowptr[i] = excl;
    fillpos[i] = excl;
    if (i == n - 1) cnt_rowptr[n] = excl + v;
  }
}

__global__ void fill_kernel(const int* __restrict__ src, const int* __restrict__ dst,
                            const float* __restrict__ ea,
                            int* __restrict__ fillpos, int2* __restrict__ csr, int ne) {
  int i = blockIdx.x * blockDim.x + threadIdx.x;
  if (i < ne) {
    int pos = atomicAdd(&fillpos[dst[i]], 1);
    csr[pos] = make_int2(src[i], __float_as_int(ea[i]));
  }
}

__global__ void row_deg_kernel(const int* __restrict__ rowptr, const int2* __restrict__ csr,
                               float* __restrict__ dinv, int n) {
  int i = blockIdx.x * blockDim.x + threadIdx.x;
  if (i >= n) return;
  int e = rowptr[i], end = rowptr[i + 1];
  float d = 2.0f;
  for (; e < end; ++e) d += __int_as_float(csr[e].y);
  dinv[i] = rsqrtf(d);
}

template <int C, bool BIAS>
__global__ void __launch_bounds__(256) gather_kernel(
    const float* __restrict__ g, const int* __restrict__ rowptr,
    const int2* __restrict__ csr, const float* __restrict__ dinv,
    const float* __restrict__ bias, float* __restrict__ agg, int n) {
  constexpr int TPN = C / 4;
  constexpr int NPB = 256 / TPN;
  const int node = blockIdx.x * NPB + threadIdx.x / TPN;
  const int cg = threadIdx.x % TPN;
  if (node >= n) return;

  const float4* __restrict__ g4 = (const float4*)g;
  float4 gs = g4[(size_t)node * TPN + cg];
  float4 acc = make_float4(2.f * gs.x, 2.f * gs.y, 2.f * gs.z, 2.f * gs.w);

  int e = rowptr[node];
  const int end = rowptr[node + 1];
  for (; e + 8 <= end; e += 8) {
    int2 ed[8];
#pragma unroll
    for (int j = 0; j < 8; ++j) ed[j] = csr[e + j];
    float4 v[8];
#pragma unroll
    for (int j = 0; j < 8; ++j) v[j] = g4[(size_t)ed[j].x * TPN + cg];
#pragma unroll
    for (int j = 0; j < 8; ++j) {
      float w = __int_as_float(ed[j].y);
      acc.x = fmaf(w, v[j].x, acc.x); acc.y = fmaf(w, v[j].y, acc.y);
      acc.z = fmaf(w, v[j].z, acc.z); acc.w = fmaf(w, v[j].w, acc.w);
    }
  }
  for (; e < end; ++e) {
    int2 ed = csr[e];
    float4 v = g4[(size_t)ed.x * TPN + cg];
    float w = __int_as_float(ed.y);
    acc.x = fmaf(w, v.x, acc.x); acc.y = fmaf(w, v.y, acc.y);
    acc.z = fmaf(w, v.z, acc.z); acc.w = fmaf(w, v.w, acc.w);
  }

  const float dn = dinv[node];
  float4 res = make_float4(dn * acc.x, dn * acc.y, dn * acc.z, dn * acc.w);
  if (BIAS) {
    float4 bv = ((const float4*)bias)[cg];
    res.x += bv.x; res.y += bv.y; res.z += bv.z; res.w += bv.w;
  }
  ((float4*)agg)[(size_t)node * TPN + cg] = res;
}

// ---------------------------------------------------------------- GEMMs

template <bool RELU_IN>
__global__ void __launch_bounds__(256) gemm128x128_kernel(
    const float* __restrict__ in, const float* __restrict__ w, const float* __restrict__ dinv,
    float* __restrict__ out, int n) {
  __shared__ float in_lds[64][132];
  const int row0 = blockIdx.x * 64;
  for (int i = threadIdx.x; i < 64 * 32; i += 256) {
    int r = i >> 5, k4 = (i & 31) << 2;
    float4 v = make_float4(0.f, 0.f, 0.f, 0.f);
    if (row0 + r < n) v = *(const float4*)(in + (size_t)(row0 + r) * 128 + k4);
    if (RELU_IN) {
      v.x = fmaxf(v.x, 0.f); v.y = fmaxf(v.y, 0.f);
      v.z = fmaxf(v.z, 0.f); v.w = fmaxf(v.w, 0.f);
    }
    *(float4*)&in_lds[r][k4] = v;
  }
  __syncthreads();

  const int rg = threadIdx.x >> 4;
  const int c0 = (threadIdx.x & 15) << 3;
  float acc[4][8];
#pragma unroll
  for (int i = 0; i < 4; ++i)
#pragma unroll
    for (int j = 0; j < 8; ++j) acc[i][j] = 0.f;

#pragma unroll 4
  for (int k = 0; k < 128; ++k) {
    float a0 = in_lds[rg * 4 + 0][k];
    float a1 = in_lds[rg * 4 + 1][k];
    float a2 = in_lds[rg * 4 + 2][k];
    float a3 = in_lds[rg * 4 + 3][k];
    float4 bl = *(const float4*)(w + (size_t)k * 128 + c0);
    float4 bh = *(const float4*)(w + (size_t)k * 128 + c0 + 4);
    float b[8] = {bl.x, bl.y, bl.z, bl.w, bh.x, bh.y, bh.z, bh.w};
#pragma unroll
    for (int j = 0; j < 8; ++j) {
      acc[0][j] = fmaf(a0, b[j], acc[0][j]);
      acc[1][j] = fmaf(a1, b[j], acc[1][j]);
      acc[2][j] = fmaf(a2, b[j], acc[2][j]);
      acc[3][j] = fmaf(a3, b[j], acc[3][j]);
    }
  }
#pragma unroll
  for (int i = 0; i < 4; ++i) {
    int r = row0 + rg * 4 + i;
    if (r < n) {
      float dn = dinv[r];
      *(float4*)(out + (size_t)r * 128 + c0) =
          make_float4(dn * acc[i][0], dn * acc[i][1], dn * acc[i][2], dn * acc[i][3]);
      *(float4*)(out + (size_t)r * 128 + c0 + 4) =
          make_float4(dn * acc[i][4], dn * acc[i][5], dn * acc[i][6], dn * acc[i][7]);
    }
  }
}

__global__ void __launch_bounds__(256) gemm16x128_kernel(
    const float* __restrict__ in, const float* __restrict__ w, const float* __restrict__ bias,
    float* __restrict__ out, int n) {
  __shared__ float in_lds[64][20];
  __shared__ float ws[16 * 128];
  __shared__ float bs[128];
  const int row0 = blockIdx.x * 64;
  for (int i = threadIdx.x; i < 16 * 32; i += 256)
    *(float4*)&ws[i * 4] = *(const float4*)(w + i * 4);
  if (threadIdx.x < 128) bs[threadIdx.x] = bias[threadIdx.x];
  for (int i = threadIdx.x; i < 64 * 4; i += 256) {
    int r = i >> 2, k4 = (i & 3) << 2;
    float4 v = make_float4(0.f, 0.f, 0.f, 0.f);
    if (row0 + r < n) v = *(const float4*)(in + (size_t)(row0 + r) * 16 + k4);
    *(float4*)&in_lds[r][k4] = v;
  }
  __syncthreads();

  const int rg = threadIdx.x >> 4;
  const int c0 = (threadIdx.x & 15) << 3;
  float acc[4][8];
#pragma unroll
  for (int i = 0; i < 4; ++i)
#pragma unroll
    for (int j = 0; j < 8; ++j) acc[i][j] = bs[c0 + j];

#pragma unroll
  for (int k = 0; k < 16; ++k) {
    float a0 = in_lds[rg * 4 + 0][k];
    float a1 = in_lds[rg * 4 + 1][k];
    float a2 = in_lds[rg * 4 + 2][k];
    float a3 = in_lds[rg * 4 + 3][k];
#pragma unroll
    for (int j = 0; j < 8; ++j) {
      float b = ws[k * 128 + c0 + j];
      acc[0][j] = fmaf(a0, b, acc[0][j]);
      acc[1][j] = fmaf(a1, b, acc[1][j]);
      acc[2][j] = fmaf(a2, b, acc[2][j]);
      acc[3][j] = fmaf(a3, b, acc[3][j]);
    }
  }
#pragma unroll
  for (int i = 0; i < 4; ++i) {
    int r = row0 + rg * 4 + i;
    if (r < n) {
#pragma unroll
      for (int j = 0; j < 8; ++j) acc[i][j] = fmaxf(acc[i][j], 0.f);
      *(float4*)(out + (size_t)r * 128 + c0) = make_float4(acc[i][0], acc[i][1], acc[i][2], acc[i][3]);
      *(float4*)(out + (size_t)r * 128 + c0 + 4) = make_float4(acc[i][4], acc[i][5], acc[i][6], acc[i][7]);
    }
  }
}

__global__ void __launch_bounds__(256) gemm128x16_kernel(
    const float* __restrict__ in, const float* __restrict__ w, const float* __restrict__ dinv,
    float* __restrict__ out, int n) {
  __shared__ float in_lds[64][132];
  __shared__ float ws[128 * 16];
  const int row0 = blockIdx.x * 64;
  for (int i = threadIdx.x; i < 128 * 4; i += 256)
    *(float4*)&ws[i * 4] = *(const float4*)(w + i * 4);
  for (int i = threadIdx.x; i < 64 * 32; i += 256) {
    int r = i >> 5, k4 = (i & 31) << 2;
    float4 v = make_float4(0.f, 0.f, 0.f, 0.f);
    if (row0 + r < n) v = *(const float4*)(in + (size_t)(row0 + r) * 128 + k4);
    v.x = fmaxf(v.x, 0.f); v.y = fmaxf(v.y, 0.f);
    v.z = fmaxf(v.z, 0.f); v.w = fmaxf(v.w, 0.f);
    *(float4*)&in_lds[r][k4] = v;
  }
  __syncthreads();

  const int rg = threadIdx.x >> 4;
  const int c = threadIdx.x & 15;
  float acc[4] = {0.f, 0.f, 0.f, 0.f};
#pragma unroll 4
  for (int k = 0; k < 128; ++k) {
    float b = ws[k * 16 + c];
    acc[0] = fmaf(in_lds[rg * 4 + 0][k], b, acc[0]);
    acc[1] = fmaf(in_lds[rg * 4 + 1][k], b, acc[1]);
    acc[2] = fmaf(in_lds[rg * 4 + 2][k], b, acc[2]);
    acc[3] = fmaf(in_lds[rg * 4 + 3][k], b, acc[3]);
  }
#pragma unroll
  for (int i = 0; i < 4; ++i) {
    int r = row0 + rg * 4 + i;
    if (r < n) out[(size_t)r * 16 + c] = dinv[r] * acc[i];
  }
}

// ---------------------------------------------------------------- launch

extern "C" void kernel_launch(void* const* d_in, const int* in_sizes, int n_in,
                              void* d_out, int out_size, void* d_ws, size_t ws_size,
                              hipStream_t stream) {
  const float* x  = (const float*)d_in[0];
  const int*   ei = (const int*)d_in[1];
  const float* ea = (const float*)d_in[2];
  const float* w0 = (const float*)d_in[3];
  const float* b0 = (const float*)d_in[4];
  const float* w1 = (const float*)d_in[5];
  const float* b1 = (const float*)d_in[6];
  const float* w2 = (const float*)d_in[7];
  const float* b2 = (const float*)d_in[8];
  const float* w3 = (const float*)d_in[9];
  const float* b3 = (const float*)d_in[10];
  float* out = (float*)d_out;

  const int* src = ei;       // edge_index[0]
  const int* dst = ei + NE;  // edge_index[1]

  const int B = 256;
  auto blocks = [](long long t) { return (int)((t + 255) / 256); };
  const int gemm_blocks = (NN + 63) / 64;  // 782

  // common workspace prefix
  float* wsf  = (float*)d_ws;
  float* bufA = wsf;                      // [NN*128]
  float* bufB = bufA + (size_t)NN * 128;  // [NN*128]
  float* dinv = bufB + (size_t)NN * 128;  // [NN]

  // padded-CSR layout
  int*  cnt_p = (int*)(dinv + ((NN + 15) & ~15));  // [NN]
  int2* csr_p = (int2*)((char*)(cnt_p + ((NN + 15) & ~15)) + 0);  // [NN*CAP]
  size_t need_pad = (size_t)((char*)(csr_p + (size_t)NN * CAP) - (char*)d_ws);

  if (ws_size >= need_pad) {
    // --- padded-CSR build: one atomic pass, no count/scan ---
    init_kernel<<<blocks(NN), B, 0, stream>>>(cnt_p, NN);
    fill_pad_kernel<<<blocks(NE), B, 0, stream>>>(src, dst, ea, cnt_p, csr_p, NE);
    row_deg_pad_kernel<<<blocks(NN), B, 0, stream>>>(cnt_p, csr_p, dinv, NN);

    xscale_kernel<<<blocks((long long)NN * 4), B, 0, stream>>>(x, dinv, bufB, NN);
    gather_pad_kernel<16, false><<<(NN + 63) / 64, B, 0, stream>>>(bufB, cnt_p, csr_p, dinv, nullptr, bufA, NN);
    gemm16x128_kernel<<<gemm_blocks, B, 0, stream>>>(bufA, w0, b0, bufB, NN);

    gemm128x128_kernel<false><<<gemm_blocks, B, 0, stream>>>(bufB, w1, dinv, bufA, NN);
    gather_pad_kernel<128, true><<<(NN + 15) / 16, B, 0, stream>>>(bufA, cnt_p, csr_p, dinv, b1, bufB, NN);

    gemm128x128_kernel<true><<<gemm_blocks, B, 0, stream>>>(bufB, w2, dinv, bufA, NN);
    gather_pad_kernel<128, true><<<(NN + 15) / 16, B, 0, stream>>>(bufA, cnt_p, csr_p, dinv, b2, bufB, NN);

    gemm128x16_kernel<<<gemm_blocks, B, 0, stream>>>(bufB, w3, dinv, bufA, NN);
    gather_pad_kernel<16, true><<<(NN + 63) / 64, B, 0, stream>>>(bufA, cnt_p, csr_p, dinv, b3, out, NN);
  } else {
    // --- compact-CSR fallback (R6 path) ---
    int*  rowptr  = (int*)(dinv + ((NN + 15) & ~15));        // [NN+1]
    int*  fillpos = rowptr + ((NN + 1 + 15) & ~15);          // [NN]
    int*  bsum    = fillpos + ((NN + 15) & ~15);             // [SCAN_NB]
    int2* csr     = (int2*)(bsum + ((SCAN_NB + 15) & ~15));  // [NE]

    init_kernel<<<blocks(NN), B, 0, stream>>>(rowptr, NN);
    count_kernel<<<blocks(NE), B, 0, stream>>>(dst, rowptr, NE);
    block_reduce_kernel<<<SCAN_NB, SCAN_B, 0, stream>>>(rowptr, bsum, NN);
    scan_bsums_kernel<<<1, SCAN_B, 0, stream>>>(bsum, SCAN_NB);
    scan_final_kernel<<<SCAN_NB, SCAN_B, 0, stream>>>(rowptr, bsum, fillpos, NN);
    fill_kernel<<<blocks(NE), B, 0, stream>>>(src, dst, ea, fillpos, csr, NE);
    row_deg_kernel<<<blocks(NN), B, 0, stream>>>(rowptr, csr, dinv, NN);

    xscale_kernel<<<blocks((long long)NN * 4), B, 0, stream>>>(x, dinv, bufB, NN);
    gather_kernel<16, false><<<(NN + 63) / 64, B, 0, stream>>>(bufB, rowptr, csr, dinv, nullptr, bufA, NN);
    gemm16x128_kernel<<<gemm_blocks, B, 0, stream>>>(bufA, w0, b0, bufB, NN);

    gemm128x128_kernel<false><<<gemm_blocks, B, 0, stream>>>(bufB, w1, dinv, bufA, NN);
    gather_kernel<128, true><<<(NN + 7) / 8, B, 0, stream>>>(bufA, rowptr, csr, dinv, b1, bufB, NN);

    gemm128x128_kernel<true><<<gemm_blocks, B, 0, stream>>>(bufB, w2, dinv, bufA, NN);
    gather_kernel<128, true><<<(NN + 7) / 8, B, 0, stream>>>(bufA, rowptr, csr, dinv, b2, bufB, NN);

    gemm128x16_kernel<<<gemm_blocks, B, 0, stream>>>(bufB, w3, dinv, bufA, NN);
    gather_kernel<16, true><<<(NN + 63) / 64, B, 0, stream>>>(bufA, rowptr, csr, dinv, b3, out, NN);
  }
}

// Round 8
// 239.505 us; speedup vs baseline: 16.7911x; 1.3563x over previous
//
#include <hip/hip_runtime.h>
#include <hip/hip_fp16.h>

// GCN, 4 layers, improved=True (self-loop weight 2.0), symmetric norm.
// N=50000 nodes, E=800000 edges, dims 16 -> 128 -> 128 -> 128 -> 16.
//
// R8: (a) fp16 staging of the gather operand g (halves L2-miss volume AND
// the cached working set); (b) padded CSR with INLINE row counter (stride
// 72 int2, 64B-aligned rows: fill's atomic + first entries share a line);
// (c) fused layer-0 GEMM pair (16->128->128, x1 in LDS; kills the x1
// round-trip and one fp32 buffer -> ws 67.4 MB, under the proven 77.2);
// (d) row_deg + xscale fused.
//
// dataflow (A = fp32 [NN*128], gbuf = fp16 [NN*128], csr inline-cnt):
//   fill -> row_deg+xscale(gbuf=xs) -> gather16(gbuf)->A16
//   fused(A16;w0,b0,w1)->gbuf(g1) -> gather128(+b1)->A
//   gemm128x128h(relu,A;w2)->gbuf(g2) -> gather128(+b2)->A
//   gemm128x16h(relu,A;w3)->gbuf(g3) -> gather16(+b3)->out

static constexpr int NN = 50000;
static constexpr int NE = 800000;
static constexpr int RSTRIDE = 72;  // int2 per row: [cnt|pad][71 entry slots]; 576 B, 64B-aligned

// ---------------------------------------------------------------- build

__global__ void init_kernel(int2* __restrict__ csr, int n) {
  int i = blockIdx.x * blockDim.x + threadIdx.x;
  if (i < n) ((int*)(csr + (size_t)i * RSTRIDE))[0] = 0;
}

__global__ void fill_pad_kernel(const int* __restrict__ src, const int* __restrict__ dst,
                                const float* __restrict__ ea, int2* __restrict__ csr, int ne) {
  int i = blockIdx.x * blockDim.x + threadIdx.x;
  if (i < ne) {
    int d = dst[i];
    int slot = atomicAdd((int*)(csr + (size_t)d * RSTRIDE), 1);
    csr[(size_t)d * RSTRIDE + 1 + slot] = make_int2(src[i], __float_as_int(ea[i]));
  }
}

// dinv[i] = rsqrt(2 + sum row weights); xs[i][:] = dinv[i] * x[i][:] (fp16)
__global__ void row_deg_xscale_kernel(const int2* __restrict__ csr, const float* __restrict__ x,
                                      float* __restrict__ dinv, __half* __restrict__ xs, int n) {
  int i = blockIdx.x * blockDim.x + threadIdx.x;
  if (i >= n) return;
  const int2* row = csr + (size_t)i * RSTRIDE;
  int cn = ((const int*)row)[0];
  float d = 2.0f;
  for (int e = 1; e <= cn; ++e) d += __int_as_float(row[e].y);
  float dn = rsqrtf(d);  // d >= 2 always (ea >= 0)
  dinv[i] = dn;
  const float4* xr = (const float4*)(x + (size_t)i * 16);
  uint2* xo = (uint2*)(xs + (size_t)i * 16);
#pragma unroll
  for (int q = 0; q < 4; ++q) {
    float4 v = xr[q];
    union { uint2 u; __half2 h[2]; } pk;
    pk.h[0] = __float22half2_rn(make_float2(dn * v.x, dn * v.y));
    pk.h[1] = __float22half2_rn(make_float2(dn * v.z, dn * v.w));
    xo[q] = pk.u;
  }
}

// ---------------------------------------------------------------- gathers (fp16 operand)

// dest[n][c] = dinv[n]*( sum_e w_e*g[src][c] + 2*g[n][c] ) (+ bias[c]);  C=16
template <bool BIAS>
__global__ void __launch_bounds__(256) gather16_kernel(
    const __half* __restrict__ g, const int2* __restrict__ csr, const float* __restrict__ dinv,
    const float* __restrict__ bias, float* __restrict__ dest, int n) {
  const int node = blockIdx.x * 64 + (threadIdx.x >> 2);
  const int cg = threadIdx.x & 3;  // 4 halfs (8 B) per lane
  if (node >= n) return;
  const uint2* g2 = (const uint2*)g;  // row = 4 uint2
  union U { uint2 u; __half2 h[2]; };
  U self; self.u = g2[(size_t)node * 4 + cg];
  float2 s0 = __half22float2(self.h[0]), s1 = __half22float2(self.h[1]);
  float4 acc = make_float4(2.f * s0.x, 2.f * s0.y, 2.f * s1.x, 2.f * s1.y);

  const int2* row = csr + (size_t)node * RSTRIDE;
  const int cn = ((const int*)row)[0];
  int e = 0;
  for (; e + 4 <= cn; e += 4) {
    int2 ed[4];
#pragma unroll
    for (int j = 0; j < 4; ++j) ed[j] = row[1 + e + j];
    U v[4];
#pragma unroll
    for (int j = 0; j < 4; ++j) v[j].u = g2[(size_t)ed[j].x * 4 + cg];
#pragma unroll
    for (int j = 0; j < 4; ++j) {
      float w = __int_as_float(ed[j].y);
      float2 f0 = __half22float2(v[j].h[0]), f1 = __half22float2(v[j].h[1]);
      acc.x = fmaf(w, f0.x, acc.x); acc.y = fmaf(w, f0.y, acc.y);
      acc.z = fmaf(w, f1.x, acc.z); acc.w = fmaf(w, f1.y, acc.w);
    }
  }
  for (; e < cn; ++e) {
    int2 ed = row[1 + e];
    U v; v.u = g2[(size_t)ed.x * 4 + cg];
    float w = __int_as_float(ed.y);
    float2 f0 = __half22float2(v.h[0]), f1 = __half22float2(v.h[1]);
    acc.x = fmaf(w, f0.x, acc.x); acc.y = fmaf(w, f0.y, acc.y);
    acc.z = fmaf(w, f1.x, acc.z); acc.w = fmaf(w, f1.y, acc.w);
  }
  float dn = dinv[node];
  float4 res = make_float4(dn * acc.x, dn * acc.y, dn * acc.z, dn * acc.w);
  if (BIAS) {
    float4 bv = ((const float4*)bias)[cg];
    res.x += bv.x; res.y += bv.y; res.z += bv.z; res.w += bv.w;
  }
  ((float4*)dest)[(size_t)node * 4 + cg] = res;
}

// C=128: 16 lanes/node, 8 halfs (16 B) per lane, 4-deep edge unroll.
template <bool BIAS>
__global__ void __launch_bounds__(256) gather128_kernel(
    const __half* __restrict__ g, const int2* __restrict__ csr, const float* __restrict__ dinv,
    const float* __restrict__ bias, float* __restrict__ agg, int n) {
  const int node = blockIdx.x * 16 + (threadIdx.x >> 4);
  const int cg = threadIdx.x & 15;
  if (node >= n) return;
  const uint4* g4 = (const uint4*)g;  // row = 16 uint4
  union U { uint4 u; __half2 h[4]; };
  float acc[8];
  {
    U self; self.u = g4[(size_t)node * 16 + cg];
    float2 f0 = __half22float2(self.h[0]), f1 = __half22float2(self.h[1]);
    float2 f2 = __half22float2(self.h[2]), f3 = __half22float2(self.h[3]);
    acc[0] = 2.f * f0.x; acc[1] = 2.f * f0.y; acc[2] = 2.f * f1.x; acc[3] = 2.f * f1.y;
    acc[4] = 2.f * f2.x; acc[5] = 2.f * f2.y; acc[6] = 2.f * f3.x; acc[7] = 2.f * f3.y;
  }
  const int2* row = csr + (size_t)node * RSTRIDE;
  const int cn = ((const int*)row)[0];
  int e = 0;
  for (; e + 4 <= cn; e += 4) {
    int2 ed[4];
#pragma unroll
    for (int j = 0; j < 4; ++j) ed[j] = row[1 + e + j];
    U v[4];
#pragma unroll
    for (int j = 0; j < 4; ++j) v[j].u = g4[(size_t)ed[j].x * 16 + cg];
#pragma unroll
    for (int j = 0; j < 4; ++j) {
      float w = __int_as_float(ed[j].y);
      float2 f0 = __half22float2(v[j].h[0]), f1 = __half22float2(v[j].h[1]);
      float2 f2 = __half22float2(v[j].h[2]), f3 = __half22float2(v[j].h[3]);
      acc[0] = fmaf(w, f0.x, acc[0]); acc[1] = fmaf(w, f0.y, acc[1]);
      acc[2] = fmaf(w, f1.x, acc[2]); acc[3] = fmaf(w, f1.y, acc[3]);
      acc[4] = fmaf(w, f2.x, acc[4]); acc[5] = fmaf(w, f2.y, acc[5]);
      acc[6] = fmaf(w, f3.x, acc[6]); acc[7] = fmaf(w, f3.y, acc[7]);
    }
  }
  for (; e < cn; ++e) {
    int2 ed = row[1 + e];
    U v; v.u = g4[(size_t)ed.x * 16 + cg];
    float w = __int_as_float(ed.y);
    float2 f0 = __half22float2(v.h[0]), f1 = __half22float2(v.h[1]);
    float2 f2 = __half22float2(v.h[2]), f3 = __half22float2(v.h[3]);
    acc[0] = fmaf(w, f0.x, acc[0]); acc[1] = fmaf(w, f0.y, acc[1]);
    acc[2] = fmaf(w, f1.x, acc[2]); acc[3] = fmaf(w, f1.y, acc[3]);
    acc[4] = fmaf(w, f2.x, acc[4]); acc[5] = fmaf(w, f2.y, acc[5]);
    acc[6] = fmaf(w, f3.x, acc[6]); acc[7] = fmaf(w, f3.y, acc[7]);
  }
  const float dn = dinv[node];
  float4 r0 = make_float4(dn * acc[0], dn * acc[1], dn * acc[2], dn * acc[3]);
  float4 r1 = make_float4(dn * acc[4], dn * acc[5], dn * acc[6], dn * acc[7]);
  if (BIAS) {
    const float4* b4 = (const float4*)bias;
    float4 bl = b4[cg * 2], bh = b4[cg * 2 + 1];
    r0.x += bl.x; r0.y += bl.y; r0.z += bl.z; r0.w += bl.w;
    r1.x += bh.x; r1.y += bh.y; r1.z += bh.z; r1.w += bh.w;
  }
  float4* o = (float4*)(agg + (size_t)node * 128 + cg * 8);
  o[0] = r0; o[1] = r1;
}

// ---------------------------------------------------------------- GEMMs

// fused layer-0: x1 = relu(agg0@w0 + b0) held in LDS; g1 = dinv .(x1@w1) in fp16.
__global__ void __launch_bounds__(256) fused_l0l1_kernel(
    const float* __restrict__ agg0, const float* __restrict__ w0, const float* __restrict__ b0,
    const float* __restrict__ w1, const float* __restrict__ dinv, __half* __restrict__ g1, int n) {
  __shared__ float a0[64][20];
  __shared__ float ws0[16 * 128];
  __shared__ float bs0[128];
  __shared__ float x1[64][132];
  const int row0 = blockIdx.x * 64;
  for (int i = threadIdx.x; i < 512; i += 256)
    ((float4*)ws0)[i] = ((const float4*)w0)[i];
  if (threadIdx.x < 128) bs0[threadIdx.x] = b0[threadIdx.x];
  {
    int i = threadIdx.x;  // 256 = 64 rows x 4 float4
    int r = i >> 2, k4 = (i & 3) << 2;
    float4 v = make_float4(0.f, 0.f, 0.f, 0.f);
    if (row0 + r < n) v = *(const float4*)(agg0 + (size_t)(row0 + r) * 16 + k4);
    *(float4*)&a0[r][k4] = v;
  }
  __syncthreads();

  const int rg = threadIdx.x >> 4;
  const int c0 = (threadIdx.x & 15) << 3;
  {
    float acc[4][8];
#pragma unroll
    for (int i = 0; i < 4; ++i)
#pragma unroll
      for (int j = 0; j < 8; ++j) acc[i][j] = bs0[c0 + j];
#pragma unroll
    for (int k = 0; k < 16; ++k) {
      float A0 = a0[rg * 4 + 0][k], A1 = a0[rg * 4 + 1][k];
      float A2 = a0[rg * 4 + 2][k], A3 = a0[rg * 4 + 3][k];
#pragma unroll
      for (int j = 0; j < 8; ++j) {
        float b = ws0[k * 128 + c0 + j];
        acc[0][j] = fmaf(A0, b, acc[0][j]);
        acc[1][j] = fmaf(A1, b, acc[1][j]);
        acc[2][j] = fmaf(A2, b, acc[2][j]);
        acc[3][j] = fmaf(A3, b, acc[3][j]);
      }
    }
#pragma unroll
    for (int i = 0; i < 4; ++i)
#pragma unroll
      for (int j = 0; j < 8; ++j) x1[rg * 4 + i][c0 + j] = fmaxf(acc[i][j], 0.f);
  }
  __syncthreads();

  float acc[4][8];
#pragma unroll
  for (int i = 0; i < 4; ++i)
#pragma unroll
    for (int j = 0; j < 8; ++j) acc[i][j] = 0.f;
#pragma unroll 4
  for (int k = 0; k < 128; ++k) {
    float A0 = x1[rg * 4 + 0][k], A1 = x1[rg * 4 + 1][k];
    float A2 = x1[rg * 4 + 2][k], A3 = x1[rg * 4 + 3][k];
    float4 bl = *(const float4*)(w1 + (size_t)k * 128 + c0);
    float4 bh = *(const float4*)(w1 + (size_t)k * 128 + c0 + 4);
    float b[8] = {bl.x, bl.y, bl.z, bl.w, bh.x, bh.y, bh.z, bh.w};
#pragma unroll
    for (int j = 0; j < 8; ++j) {
      acc[0][j] = fmaf(A0, b[j], acc[0][j]);
      acc[1][j] = fmaf(A1, b[j], acc[1][j]);
      acc[2][j] = fmaf(A2, b[j], acc[2][j]);
      acc[3][j] = fmaf(A3, b[j], acc[3][j]);
    }
  }
#pragma unroll
  for (int i = 0; i < 4; ++i) {
    int r = row0 + rg * 4 + i;
    if (r < n) {
      float dn = dinv[r];
      union { uint4 u; __half2 h[4]; } pk;
      pk.h[0] = __float22half2_rn(make_float2(dn * acc[i][0], dn * acc[i][1]));
      pk.h[1] = __float22half2_rn(make_float2(dn * acc[i][2], dn * acc[i][3]));
      pk.h[2] = __float22half2_rn(make_float2(dn * acc[i][4], dn * acc[i][5]));
      pk.h[3] = __float22half2_rn(make_float2(dn * acc[i][6], dn * acc[i][7]));
      *(uint4*)(g1 + (size_t)r * 128 + c0) = pk.u;
    }
  }
}

// 128 -> 128, relu on staged input, fp16 packed output g = dinv.(relu(in)@w)
__global__ void __launch_bounds__(256) gemm128x128h_kernel(
    const float* __restrict__ in, const float* __restrict__ w, const float* __restrict__ dinv,
    __half* __restrict__ out, int n) {
  __shared__ float in_lds[64][132];
  const int row0 = blockIdx.x * 64;
  for (int i = threadIdx.x; i < 64 * 32; i += 256) {
    int r = i >> 5, k4 = (i & 31) << 2;
    float4 v = make_float4(0.f, 0.f, 0.f, 0.f);
    if (row0 + r < n) v = *(const float4*)(in + (size_t)(row0 + r) * 128 + k4);
    v.x = fmaxf(v.x, 0.f); v.y = fmaxf(v.y, 0.f);
    v.z = fmaxf(v.z, 0.f); v.w = fmaxf(v.w, 0.f);
    *(float4*)&in_lds[r][k4] = v;
  }
  __syncthreads();

  const int rg = threadIdx.x >> 4;
  const int c0 = (threadIdx.x & 15) << 3;
  float acc[4][8];
#pragma unroll
  for (int i = 0; i < 4; ++i)
#pragma unroll
    for (int j = 0; j < 8; ++j) acc[i][j] = 0.f;
#pragma unroll 4
  for (int k = 0; k < 128; ++k) {
    float A0 = in_lds[rg * 4 + 0][k], A1 = in_lds[rg * 4 + 1][k];
    float A2 = in_lds[rg * 4 + 2][k], A3 = in_lds[rg * 4 + 3][k];
    float4 bl = *(const float4*)(w + (size_t)k * 128 + c0);
    float4 bh = *(const float4*)(w + (size_t)k * 128 + c0 + 4);
    float b[8] = {bl.x, bl.y, bl.z, bl.w, bh.x, bh.y, bh.z, bh.w};
#pragma unroll
    for (int j = 0; j < 8; ++j) {
      acc[0][j] = fmaf(A0, b[j], acc[0][j]);
      acc[1][j] = fmaf(A1, b[j], acc[1][j]);
      acc[2][j] = fmaf(A2, b[j], acc[2][j]);
      acc[3][j] = fmaf(A3, b[j], acc[3][j]);
    }
  }
#pragma unroll
  for (int i = 0; i < 4; ++i) {
    int r = row0 + rg * 4 + i;
    if (r < n) {
      float dn = dinv[r];
      union { uint4 u; __half2 h[4]; } pk;
      pk.h[0] = __float22half2_rn(make_float2(dn * acc[i][0], dn * acc[i][1]));
      pk.h[1] = __float22half2_rn(make_float2(dn * acc[i][2], dn * acc[i][3]));
      pk.h[2] = __float22half2_rn(make_float2(dn * acc[i][4], dn * acc[i][5]));
      pk.h[3] = __float22half2_rn(make_float2(dn * acc[i][6], dn * acc[i][7]));
      *(uint4*)(out + (size_t)r * 128 + c0) = pk.u;
    }
  }
}

// 128 -> 16, relu on staged input, fp16 output g3 = dinv.(relu(in)@w3)
__global__ void __launch_bounds__(256) gemm128x16h_kernel(
    const float* __restrict__ in, const float* __restrict__ w, const float* __restrict__ dinv,
    __half* __restrict__ out, int n) {
  __shared__ float in_lds[64][132];
  __shared__ float ws[128 * 16];
  const int row0 = blockIdx.x * 64;
  for (int i = threadIdx.x; i < 128 * 4; i += 256)
    ((float4*)ws)[i] = ((const float4*)w)[i];
  for (int i = threadIdx.x; i < 64 * 32; i += 256) {
    int r = i >> 5, k4 = (i & 31) << 2;
    float4 v = make_float4(0.f, 0.f, 0.f, 0.f);
    if (row0 + r < n) v = *(const float4*)(in + (size_t)(row0 + r) * 128 + k4);
    v.x = fmaxf(v.x, 0.f); v.y = fmaxf(v.y, 0.f);
    v.z = fmaxf(v.z, 0.f); v.w = fmaxf(v.w, 0.f);
    *(float4*)&in_lds[r][k4] = v;
  }
  __syncthreads();

  const int rg = threadIdx.x >> 4;
  const int c = threadIdx.x & 15;
  float acc[4] = {0.f, 0.f, 0.f, 0.f};
#pragma unroll 4
  for (int k = 0; k < 128; ++k) {
    float b = ws[k * 16 + c];
    acc[0] = fmaf(in_lds[rg * 4 + 0][k], b, acc[0]);
    acc[1] = fmaf(in_lds[rg * 4 + 1][k], b, acc[1]);
    acc[2] = fmaf(in_lds[rg * 4 + 2][k], b, acc[2]);
    acc[3] = fmaf(in_lds[rg * 4 + 3][k], b, acc[3]);
  }
#pragma unroll
  for (int i = 0; i < 4; ++i) {
    int r = row0 + rg * 4 + i;
    if (r < n) out[(size_t)r * 16 + c] = __float2half(dinv[r] * acc[i]);
  }
}

// ---------------------------------------------------------------- launch

extern "C" void kernel_launch(void* const* d_in, const int* in_sizes, int n_in,
                              void* d_out, int out_size, void* d_ws, size_t ws_size,
                              hipStream_t stream) {
  const float* x  = (const float*)d_in[0];
  const int*   ei = (const int*)d_in[1];
  const float* ea = (const float*)d_in[2];
  const float* w0 = (const float*)d_in[3];
  const float* b0 = (const float*)d_in[4];
  const float* w1 = (const float*)d_in[5];
  const float* b1 = (const float*)d_in[6];
  const float* w2 = (const float*)d_in[7];
  const float* b2 = (const float*)d_in[8];
  const float* w3 = (const float*)d_in[9];
  const float* b3 = (const float*)d_in[10];
  float* out = (float*)d_out;

  const int* src = ei;       // edge_index[0]
  const int* dst = ei + NE;  // edge_index[1]

  // workspace: A fp32 [NN*128] | gbuf fp16 [NN*128] | dinv [NN] | csr [NN*RSTRIDE int2]
  // total ~67.4 MB (< 77.2 MB proven available by R7's padded branch executing).
  float*  A    = (float*)d_ws;
  __half* gbuf = (__half*)(A + (size_t)NN * 128);
  float*  dinv = (float*)(gbuf + (size_t)NN * 128);
  int2*   csr  = (int2*)(dinv + ((NN + 15) & ~15));

  const int B = 256;
  auto blocks = [](long long t) { return (int)((t + 255) / 256); };
  const int gemm_blocks = (NN + 63) / 64;  // 782

  // build
  init_kernel<<<blocks(NN), B, 0, stream>>>(csr, NN);
  fill_pad_kernel<<<blocks(NE), B, 0, stream>>>(src, dst, ea, csr, NE);
  row_deg_xscale_kernel<<<blocks(NN), B, 0, stream>>>(csr, x, dinv, gbuf, NN);

  // layer 0: gather xs(16ch) -> A16, fused (x1 in LDS) -> g1 fp16
  gather16_kernel<false><<<(NN + 63) / 64, B, 0, stream>>>(gbuf, csr, dinv, nullptr, A, NN);
  fused_l0l1_kernel<<<gemm_blocks, B, 0, stream>>>(A, w0, b0, w1, dinv, gbuf, NN);

  // layer 1: gather g1 -> agg1 (A)
  gather128_kernel<true><<<(NN + 15) / 16, B, 0, stream>>>(gbuf, csr, dinv, b1, A, NN);

  // layer 2: gemm relu(A)@w2 -> g2 fp16, gather -> agg2 (A)
  gemm128x128h_kernel<<<gemm_blocks, B, 0, stream>>>(A, w2, dinv, gbuf, NN);
  gather128_kernel<true><<<(NN + 15) / 16, B, 0, stream>>>(gbuf, csr, dinv, b2, A, NN);

  // layer 3: gemm relu(A)@w3 -> g3 fp16 (16ch), gather -> out
  gemm128x16h_kernel<<<gemm_blocks, B, 0, stream>>>(A, w3, dinv, gbuf, NN);
  gather16_kernel<true><<<(NN + 63) / 64, B, 0, stream>>>(gbuf, csr, dinv, b3, out, NN);
}

// Round 9
// 189.009 us; speedup vs baseline: 21.2769x; 1.2672x over previous
//
#include <hip/hip_runtime.h>
#include <hip/hip_fp16.h>

// GCN, 4 layers, improved=True (self-loop weight 2.0), symmetric norm.
// N=50000 nodes, E=800000 edges, dims 16 -> 128 -> 128 -> 128 -> 16.
//
// R9: MFMA (f32_16x16x32_f16) for the three big GEMMs, fp16 aggregation
// buffer end-to-end (gather writes relu(agg+b) as fp16), weights pre-
// converted once per launch to fp16 transposed+XOR-swizzled buffers.
// Operand layouts: A/B row|col = lane&15, k = (lane>>4)*4 + {0..3} in two
// 16-k blocks (elems 0-3 -> k, elems 4-7 -> k+16); C/D col = lane&15,
// row = (lane>>4)*4 + reg (m89-verified).
//
// dataflow (Ah fp16 [NN*128], gbuf fp16 [NN*128]):
//   init -> fill -> prep_wt -> row_deg_xscale(gbuf=xs)
//   gather16(gbuf)->Ah16 ; fused_l0l1(Ah16;w0,b0,wt1)->gbuf(g1)
//   gather128(+b1,relu)->Ah ; mfma128x128(Ah;wt2)->gbuf(g2)
//   gather128(+b2,relu)->Ah ; mfma128x16(Ah;wt3)->gbuf(g3)
//   gather16_final(+b3)->out fp32

static constexpr int NN = 50000;
static constexpr int NE = 800000;
static constexpr int RSTRIDE = 72;  // int2 per row: [cnt|pad][71 entry slots]

typedef _Float16 half8_t __attribute__((ext_vector_type(8)));
typedef float float4_t __attribute__((ext_vector_type(4)));

union Frag { uint4 u; half8_t h; };
union H2U2 { uint2 u; __half2 h[2]; };
union H4U4 { uint4 u; __half2 h[4]; };

// ---------------------------------------------------------------- build

__global__ void init_kernel(int2* __restrict__ csr, int n) {
  int i = blockIdx.x * blockDim.x + threadIdx.x;
  if (i < n) ((int*)(csr + (size_t)i * RSTRIDE))[0] = 0;
}

__global__ void fill_pad_kernel(const int* __restrict__ src, const int* __restrict__ dst,
                                const float* __restrict__ ea, int2* __restrict__ csr, int ne) {
  int i = blockIdx.x * blockDim.x + threadIdx.x;
  if (i < ne) {
    int d = dst[i];
    int slot = atomicAdd((int*)(csr + (size_t)d * RSTRIDE), 1);
    csr[(size_t)d * RSTRIDE + 1 + slot] = make_int2(src[i], __float_as_int(ea[i]));
  }
}

// w1,w2 [128][128] and w3 [128][16] -> fp16, transposed [n][k], XOR-swizzled:
// half at byte  n*256 + ((2k) ^ ((n&7)<<4))  within each wt buffer.
__global__ void prep_wt_kernel(const float* __restrict__ w1, const float* __restrict__ w2,
                               const float* __restrict__ w3, char* __restrict__ wt1,
                               char* __restrict__ wt2, char* __restrict__ wt3) {
  int t = blockIdx.x * blockDim.x + threadIdx.x;
  if (t < 16384) {
    int k = t >> 7, n = t & 127;
    *(ushort*)(wt1 + n * 256 + ((2 * k) ^ ((n & 7) << 4))) = __half_as_ushort(__float2half(w1[t]));
  } else if (t < 32768) {
    int t2 = t - 16384;
    int k = t2 >> 7, n = t2 & 127;
    *(ushort*)(wt2 + n * 256 + ((2 * k) ^ ((n & 7) << 4))) = __half_as_ushort(__float2half(w2[t2]));
  } else if (t < 34816) {
    int t2 = t - 32768;
    int k = t2 >> 4, n = t2 & 15;
    *(ushort*)(wt3 + n * 256 + ((2 * k) ^ ((n & 7) << 4))) = __half_as_ushort(__float2half(w3[t2]));
  }
}

// dinv[i] = rsqrt(2 + sum row weights); xs[i][:] = dinv[i] * x[i][:] (fp16)
__global__ void row_deg_xscale_kernel(const int2* __restrict__ csr, const float* __restrict__ x,
                                      float* __restrict__ dinv, __half* __restrict__ xs, int n) {
  int i = blockIdx.x * blockDim.x + threadIdx.x;
  if (i >= n) return;
  const int2* row = csr + (size_t)i * RSTRIDE;
  int cn = ((const int*)row)[0];
  float d = 2.0f;
  for (int e = 1; e <= cn; ++e) d += __int_as_float(row[e].y);
  float dn = rsqrtf(d);  // d >= 2 always (ea >= 0)
  dinv[i] = dn;
  const float4* xr = (const float4*)(x + (size_t)i * 16);
  uint2* xo = (uint2*)(xs + (size_t)i * 16);
#pragma unroll
  for (int q = 0; q < 4; ++q) {
    float4 v = xr[q];
    H2U2 pk;
    pk.h[0] = __float22half2_rn(make_float2(dn * v.x, dn * v.y));
    pk.h[1] = __float22half2_rn(make_float2(dn * v.z, dn * v.w));
    xo[q] = pk.u;
  }
}

// ---------------------------------------------------------------- gathers

// C=16. FINAL: out fp32 +bias. else: out fp16, no bias (feeds fused GEMM).
template <bool FINAL>
__global__ void __launch_bounds__(256) gather16_kernel(
    const __half* __restrict__ g, const int2* __restrict__ csr, const float* __restrict__ dinv,
    const float* __restrict__ bias, void* __restrict__ dest, int n) {
  const int node = blockIdx.x * 64 + (threadIdx.x >> 2);
  const int cg = threadIdx.x & 3;  // 4 halfs (8 B) per lane
  if (node >= n) return;
  const uint2* g2 = (const uint2*)g;
  H2U2 self; self.u = g2[(size_t)node * 4 + cg];
  float2 s0 = __half22float2(self.h[0]), s1 = __half22float2(self.h[1]);
  float4 acc = make_float4(2.f * s0.x, 2.f * s0.y, 2.f * s1.x, 2.f * s1.y);

  const int2* row = csr + (size_t)node * RSTRIDE;
  const int cn = ((const int*)row)[0];
  int e = 0;
  for (; e + 4 <= cn; e += 4) {
    int2 ed[4];
#pragma unroll
    for (int j = 0; j < 4; ++j) ed[j] = row[1 + e + j];
    H2U2 v[4];
#pragma unroll
    for (int j = 0; j < 4; ++j) v[j].u = g2[(size_t)ed[j].x * 4 + cg];
#pragma unroll
    for (int j = 0; j < 4; ++j) {
      float w = __int_as_float(ed[j].y);
      float2 f0 = __half22float2(v[j].h[0]), f1 = __half22float2(v[j].h[1]);
      acc.x = fmaf(w, f0.x, acc.x); acc.y = fmaf(w, f0.y, acc.y);
      acc.z = fmaf(w, f1.x, acc.z); acc.w = fmaf(w, f1.y, acc.w);
    }
  }
  for (; e < cn; ++e) {
    int2 ed = row[1 + e];
    H2U2 v; v.u = g2[(size_t)ed.x * 4 + cg];
    float w = __int_as_float(ed.y);
    float2 f0 = __half22float2(v.h[0]), f1 = __half22float2(v.h[1]);
    acc.x = fmaf(w, f0.x, acc.x); acc.y = fmaf(w, f0.y, acc.y);
    acc.z = fmaf(w, f1.x, acc.z); acc.w = fmaf(w, f1.y, acc.w);
  }
  float dn = dinv[node];
  if (FINAL) {
    float4 bv = ((const float4*)bias)[cg];
    float4 res = make_float4(dn * acc.x + bv.x, dn * acc.y + bv.y,
                             dn * acc.z + bv.z, dn * acc.w + bv.w);
    ((float4*)dest)[(size_t)node * 4 + cg] = res;
  } else {
    H2U2 pk;
    pk.h[0] = __float22half2_rn(make_float2(dn * acc.x, dn * acc.y));
    pk.h[1] = __float22half2_rn(make_float2(dn * acc.z, dn * acc.w));
    ((uint2*)dest)[(size_t)node * 4 + cg] = pk.u;
  }
}

// C=128, 16 lanes/node: out = relu(dinv*sum + bias) packed fp16 (MFMA input).
__global__ void __launch_bounds__(256) gather128_kernel(
    const __half* __restrict__ g, const int2* __restrict__ csr, const float* __restrict__ dinv,
    const float* __restrict__ bias, __half* __restrict__ aggh, int n) {
  const int node = blockIdx.x * 16 + (threadIdx.x >> 4);
  const int cg = threadIdx.x & 15;
  if (node >= n) return;
  const uint4* g4 = (const uint4*)g;  // row = 16 uint4
  float acc[8];
  {
    H4U4 self; self.u = g4[(size_t)node * 16 + cg];
    float2 f0 = __half22float2(self.h[0]), f1 = __half22float2(self.h[1]);
    float2 f2 = __half22float2(self.h[2]), f3 = __half22float2(self.h[3]);
    acc[0] = 2.f * f0.x; acc[1] = 2.f * f0.y; acc[2] = 2.f * f1.x; acc[3] = 2.f * f1.y;
    acc[4] = 2.f * f2.x; acc[5] = 2.f * f2.y; acc[6] = 2.f * f3.x; acc[7] = 2.f * f3.y;
  }
  const int2* row = csr + (size_t)node * RSTRIDE;
  const int cn = ((const int*)row)[0];
  int e = 0;
  for (; e + 4 <= cn; e += 4) {
    int2 ed[4];
#pragma unroll
    for (int j = 0; j < 4; ++j) ed[j] = row[1 + e + j];
    H4U4 v[4];
#pragma unroll
    for (int j = 0; j < 4; ++j) v[j].u = g4[(size_t)ed[j].x * 16 + cg];
#pragma unroll
    for (int j = 0; j < 4; ++j) {
      float w = __int_as_float(ed[j].y);
      float2 f0 = __half22float2(v[j].h[0]), f1 = __half22float2(v[j].h[1]);
      float2 f2 = __half22float2(v[j].h[2]), f3 = __half22float2(v[j].h[3]);
      acc[0] = fmaf(w, f0.x, acc[0]); acc[1] = fmaf(w, f0.y, acc[1]);
      acc[2] = fmaf(w, f1.x, acc[2]); acc[3] = fmaf(w, f1.y, acc[3]);
      acc[4] = fmaf(w, f2.x, acc[4]); acc[5] = fmaf(w, f2.y, acc[5]);
      acc[6] = fmaf(w, f3.x, acc[6]); acc[7] = fmaf(w, f3.y, acc[7]);
    }
  }
  for (; e < cn; ++e) {
    int2 ed = row[1 + e];
    H4U4 v; v.u = g4[(size_t)ed.x * 16 + cg];
    float w = __int_as_float(ed.y);
    float2 f0 = __half22float2(v.h[0]), f1 = __half22float2(v.h[1]);
    float2 f2 = __half22float2(v.h[2]), f3 = __half22float2(v.h[3]);
    acc[0] = fmaf(w, f0.x, acc[0]); acc[1] = fmaf(w, f0.y, acc[1]);
    acc[2] = fmaf(w, f1.x, acc[2]); acc[3] = fmaf(w, f1.y, acc[3]);
    acc[4] = fmaf(w, f2.x, acc[4]); acc[5] = fmaf(w, f2.y, acc[5]);
    acc[6] = fmaf(w, f3.x, acc[6]); acc[7] = fmaf(w, f3.y, acc[7]);
  }
  const float dn = dinv[node];
  const float4* b4 = (const float4*)bias;
  float4 bl = b4[cg * 2], bh = b4[cg * 2 + 1];
  float r[8];
  r[0] = fmaxf(dn * acc[0] + bl.x, 0.f); r[1] = fmaxf(dn * acc[1] + bl.y, 0.f);
  r[2] = fmaxf(dn * acc[2] + bl.z, 0.f); r[3] = fmaxf(dn * acc[3] + bl.w, 0.f);
  r[4] = fmaxf(dn * acc[4] + bh.x, 0.f); r[5] = fmaxf(dn * acc[5] + bh.y, 0.f);
  r[6] = fmaxf(dn * acc[6] + bh.z, 0.f); r[7] = fmaxf(dn * acc[7] + bh.w, 0.f);
  H4U4 pk;
  pk.h[0] = __float22half2_rn(make_float2(r[0], r[1]));
  pk.h[1] = __float22half2_rn(make_float2(r[2], r[3]));
  pk.h[2] = __float22half2_rn(make_float2(r[4], r[5]));
  pk.h[3] = __float22half2_rn(make_float2(r[6], r[7]));
  ((uint4*)aggh)[(size_t)node * 16 + cg] = pk.u;
}

// ---------------------------------------------------------------- MFMA GEMMs

// g2 = dinv .( Ah @ w2 ),  Ah fp16 [n][128] (already relu'd), wt pre-swizzled.
__global__ void __launch_bounds__(256) mfma128x128_kernel(
    const __half* __restrict__ Ah, const char* __restrict__ wt,
    const float* __restrict__ dinv, __half* __restrict__ outg, int n) {
  __shared__ char wts[32768];
  for (int i = threadIdx.x; i < 2048; i += 256)
    ((uint4*)wts)[i] = ((const uint4*)wt)[i];
  __syncthreads();
  const int row0 = blockIdx.x * 64;
  const int wave = threadIdx.x >> 6, lane = threadIdx.x & 63;
  const int lr = lane & 15, hi = lane >> 4;
  const int rowL = wave * 16 + lr;
  const char* Arow = (const char*)(Ah + (size_t)(row0 + rowL) * 128);
  const int sw = (lr & 7) << 4;
  float4_t acc[8];
#pragma unroll
  for (int ct = 0; ct < 8; ++ct) acc[ct] = (float4_t){0.f, 0.f, 0.f, 0.f};
#pragma unroll
  for (int k0 = 0; k0 < 128; k0 += 32) {
    const int kb = 2 * k0 + hi * 8;
    uint2 alo = *(const uint2*)(Arow + kb);
    uint2 ahi2 = *(const uint2*)(Arow + kb + 32);
    Frag a; a.u = make_uint4(alo.x, alo.y, ahi2.x, ahi2.y);
#pragma unroll
    for (int ct = 0; ct < 8; ++ct) {
      const char* brow = wts + (ct * 16 + lr) * 256;
      uint2 blo = *(const uint2*)(brow + (kb ^ sw));
      uint2 bhi2 = *(const uint2*)(brow + ((kb + 32) ^ sw));
      Frag b; b.u = make_uint4(blo.x, blo.y, bhi2.x, bhi2.y);
      acc[ct] = __builtin_amdgcn_mfma_f32_16x16x32_f16(a.h, b.h, acc[ct], 0, 0, 0);
    }
  }
  int rr[4]; float dnv[4];
#pragma unroll
  for (int reg = 0; reg < 4; ++reg) {
    rr[reg] = row0 + wave * 16 + hi * 4 + reg;
    dnv[reg] = (rr[reg] < n) ? dinv[rr[reg]] : 0.f;
  }
#pragma unroll
  for (int ct = 0; ct < 8; ++ct) {
    int c = ct * 16 + lr;
#pragma unroll
    for (int reg = 0; reg < 4; ++reg)
      if (rr[reg] < n)
        outg[(size_t)rr[reg] * 128 + c] = __float2half(dnv[reg] * acc[ct][reg]);
  }
}

// g3 = dinv .( Ah @ w3 ), 128 -> 16.
__global__ void __launch_bounds__(256) mfma128x16_kernel(
    const __half* __restrict__ Ah, const char* __restrict__ wt,
    const float* __restrict__ dinv, __half* __restrict__ outg, int n) {
  __shared__ char wts[4096];
  if (threadIdx.x < 256) ((uint4*)wts)[threadIdx.x] = ((const uint4*)wt)[threadIdx.x];
  __syncthreads();
  const int row0 = blockIdx.x * 64;
  const int wave = threadIdx.x >> 6, lane = threadIdx.x & 63;
  const int lr = lane & 15, hi = lane >> 4;
  const int rowL = wave * 16 + lr;
  const char* Arow = (const char*)(Ah + (size_t)(row0 + rowL) * 128);
  const int sw = (lr & 7) << 4;
  const char* brow = wts + lr * 256;
  float4_t acc = (float4_t){0.f, 0.f, 0.f, 0.f};
#pragma unroll
  for (int k0 = 0; k0 < 128; k0 += 32) {
    const int kb = 2 * k0 + hi * 8;
    uint2 alo = *(const uint2*)(Arow + kb);
    uint2 ahi2 = *(const uint2*)(Arow + kb + 32);
    Frag a; a.u = make_uint4(alo.x, alo.y, ahi2.x, ahi2.y);
    uint2 blo = *(const uint2*)(brow + (kb ^ sw));
    uint2 bhi2 = *(const uint2*)(brow + ((kb + 32) ^ sw));
    Frag b; b.u = make_uint4(blo.x, blo.y, bhi2.x, bhi2.y);
    acc = __builtin_amdgcn_mfma_f32_16x16x32_f16(a.h, b.h, acc, 0, 0, 0);
  }
#pragma unroll
  for (int reg = 0; reg < 4; ++reg) {
    int r = row0 + wave * 16 + hi * 4 + reg;
    if (r < n) outg[(size_t)r * 16 + lr] = __float2half(dinv[r] * acc[reg]);
  }
}

// fused layer-0: x1 = relu(A16h@w0 + b0) (VALU, K=16) -> swizzled fp16 LDS;
// g1 = dinv .( x1 @ w1 ) via MFMA.
__global__ void __launch_bounds__(256) fused_l0l1_kernel(
    const __half* __restrict__ A16h, const float* __restrict__ w0, const float* __restrict__ b0,
    const char* __restrict__ wt1, const float* __restrict__ dinv, __half* __restrict__ g1, int n) {
  __shared__ float a0[64][17];
  __shared__ float ws0[16 * 128];
  __shared__ float bs0[128];
  __shared__ char wts[32768];
  __shared__ char x1s[16384];
  const int row0 = blockIdx.x * 64;
  for (int i = threadIdx.x; i < 2048; i += 256)
    ((uint4*)wts)[i] = ((const uint4*)wt1)[i];
  for (int i = threadIdx.x; i < 512; i += 256)
    ((float4*)ws0)[i] = ((const float4*)w0)[i];
  if (threadIdx.x < 128) bs0[threadIdx.x] = b0[threadIdx.x];
  {
    int r = threadIdx.x >> 2, c8 = threadIdx.x & 3;
    H2U2 v; v.u = make_uint2(0u, 0u);
    if (row0 + r < n) v.u = ((const uint2*)(A16h + (size_t)(row0 + r) * 16))[c8];
    float2 f0 = __half22float2(v.h[0]), f1 = __half22float2(v.h[1]);
    a0[r][c8 * 4 + 0] = f0.x; a0[r][c8 * 4 + 1] = f0.y;
    a0[r][c8 * 4 + 2] = f1.x; a0[r][c8 * 4 + 3] = f1.y;
  }
  __syncthreads();

  // GEMM1 (VALU): x1 = relu(a0 @ w0 + b0) -> x1s (swizzled fp16)
  {
    const int rg = threadIdx.x >> 4;
    const int c0 = (threadIdx.x & 15) << 3;
    float acc1[4][8];
#pragma unroll
    for (int i = 0; i < 4; ++i)
#pragma unroll
      for (int j = 0; j < 8; ++j) acc1[i][j] = bs0[c0 + j];
#pragma unroll
    for (int k = 0; k < 16; ++k) {
      float A0 = a0[rg * 4 + 0][k], A1 = a0[rg * 4 + 1][k];
      float A2 = a0[rg * 4 + 2][k], A3 = a0[rg * 4 + 3][k];
#pragma unroll
      for (int j = 0; j < 8; ++j) {
        float b = ws0[k * 128 + c0 + j];
        acc1[0][j] = fmaf(A0, b, acc1[0][j]);
        acc1[1][j] = fmaf(A1, b, acc1[1][j]);
        acc1[2][j] = fmaf(A2, b, acc1[2][j]);
        acc1[3][j] = fmaf(A3, b, acc1[3][j]);
      }
    }
#pragma unroll
    for (int i = 0; i < 4; ++i) {
      int row = rg * 4 + i;
      int swz = (row & 7) << 4;
#pragma unroll
      for (int jp = 0; jp < 4; ++jp) {
        int j = jp * 2;
        __half2 h = __float22half2_rn(make_float2(fmaxf(acc1[i][j], 0.f), fmaxf(acc1[i][j + 1], 0.f)));
        *(uint*)(x1s + row * 256 + ((2 * (c0 + j)) ^ swz)) = *(uint*)&h;
      }
    }
  }
  __syncthreads();

  // GEMM2 (MFMA): g1 = dinv .( x1 @ w1 )
  const int wave = threadIdx.x >> 6, lane = threadIdx.x & 63;
  const int lr = lane & 15, hi = lane >> 4;
  const int rowL = wave * 16 + lr;
  const char* Arow = x1s + rowL * 256;
  const int swa = (rowL & 7) << 4;
  const int swb = (lr & 7) << 4;
  float4_t acc[8];
#pragma unroll
  for (int ct = 0; ct < 8; ++ct) acc[ct] = (float4_t){0.f, 0.f, 0.f, 0.f};
#pragma unroll
  for (int k0 = 0; k0 < 128; k0 += 32) {
    const int kb = 2 * k0 + hi * 8;
    uint2 alo = *(const uint2*)(Arow + (kb ^ swa));
    uint2 ahi2 = *(const uint2*)(Arow + ((kb + 32) ^ swa));
    Frag a; a.u = make_uint4(alo.x, alo.y, ahi2.x, ahi2.y);
#pragma unroll
    for (int ct = 0; ct < 8; ++ct) {
      const char* brow = wts + (ct * 16 + lr) * 256;
      uint2 blo = *(const uint2*)(brow + (kb ^ swb));
      uint2 bhi2 = *(const uint2*)(brow + ((kb + 32) ^ swb));
      Frag b; b.u = make_uint4(blo.x, blo.y, bhi2.x, bhi2.y);
      acc[ct] = __builtin_amdgcn_mfma_f32_16x16x32_f16(a.h, b.h, acc[ct], 0, 0, 0);
    }
  }
  int rr[4]; float dnv[4];
#pragma unroll
  for (int reg = 0; reg < 4; ++reg) {
    rr[reg] = row0 + wave * 16 + hi * 4 + reg;
    dnv[reg] = (rr[reg] < n) ? dinv[rr[reg]] : 0.f;
  }
#pragma unroll
  for (int ct = 0; ct < 8; ++ct) {
    int c = ct * 16 + lr;
#pragma unroll
    for (int reg = 0; reg < 4; ++reg)
      if (rr[reg] < n)
        g1[(size_t)rr[reg] * 128 + c] = __float2half(dnv[reg] * acc[ct][reg]);
  }
}

// ---------------------------------------------------------------- launch

extern "C" void kernel_launch(void* const* d_in, const int* in_sizes, int n_in,
                              void* d_out, int out_size, void* d_ws, size_t ws_size,
                              hipStream_t stream) {
  const float* x  = (const float*)d_in[0];
  const int*   ei = (const int*)d_in[1];
  const float* ea = (const float*)d_in[2];
  const float* w0 = (const float*)d_in[3];
  const float* b0 = (const float*)d_in[4];
  const float* w1 = (const float*)d_in[5];
  const float* b1 = (const float*)d_in[6];
  const float* w2 = (const float*)d_in[7];
  const float* b2 = (const float*)d_in[8];
  const float* w3 = (const float*)d_in[9];
  const float* b3 = (const float*)d_in[10];
  float* out = (float*)d_out;

  const int* src = ei;       // edge_index[0]
  const int* dst = ei + NE;  // edge_index[1]

  // workspace: Ah fp16 | gbuf fp16 | dinv | wt1 | wt2 | wt3 | csr  (~54.6 MB)
  __half* Ah   = (__half*)d_ws;
  __half* gbuf = Ah + (size_t)NN * 128;
  float*  dinv = (float*)(gbuf + (size_t)NN * 128);
  char*   wt1  = (char*)(dinv + ((NN + 63) & ~63));
  char*   wt2  = wt1 + 32768;
  char*   wt3  = wt2 + 32768;
  int2*   csr  = (int2*)(wt3 + 4096);

  const int B = 256;
  auto blocks = [](long long t) { return (int)((t + 255) / 256); };
  const int gemm_blocks = (NN + 63) / 64;  // 782

  // build
  init_kernel<<<blocks(NN), B, 0, stream>>>(csr, NN);
  fill_pad_kernel<<<blocks(NE), B, 0, stream>>>(src, dst, ea, csr, NE);
  prep_wt_kernel<<<136, B, 0, stream>>>(w1, w2, w3, wt1, wt2, wt3);
  row_deg_xscale_kernel<<<blocks(NN), B, 0, stream>>>(csr, x, dinv, gbuf, NN);

  // layer 0: gather xs(16ch fp16) -> Ah16, fused -> g1 fp16
  gather16_kernel<false><<<(NN + 63) / 64, B, 0, stream>>>(gbuf, csr, dinv, nullptr, Ah, NN);
  fused_l0l1_kernel<<<gemm_blocks, B, 0, stream>>>(Ah, w0, b0, wt1, dinv, gbuf, NN);

  // layer 1: gather g1 (+b1, relu) -> Ah fp16 ; MFMA @w2 -> g2
  gather128_kernel<<<(NN + 15) / 16, B, 0, stream>>>(gbuf, csr, dinv, b1, Ah, NN);
  mfma128x128_kernel<<<gemm_blocks, B, 0, stream>>>(Ah, wt2, dinv, gbuf, NN);

  // layer 2: gather g2 (+b2, relu) -> Ah ; MFMA @w3 -> g3 (16ch)
  gather128_kernel<<<(NN + 15) / 16, B, 0, stream>>>(gbuf, csr, dinv, b2, Ah, NN);
  mfma128x16_kernel<<<gemm_blocks, B, 0, stream>>>(Ah, wt3, dinv, gbuf, NN);

  // layer 3: final gather (+b3) -> out fp32
  gather16_kernel<true><<<(NN + 63) / 64, B, 0, stream>>>(gbuf, csr, dinv, b3, out, NN);
}